// Round 1
// baseline (6461.532 us; speedup 1.0000x reference)
//
#include <hip/hip_runtime.h>
#include <math.h>

__device__ __forceinline__ float sigmoidf_(float x){ return 1.0f/(1.0f+__expf(-x)); }

// Build WhhP[j*192 + g*64 + k] = Whh[(g*64+j)*64 + k]   (j=output feat, g=gate r/z/n, k=input feat)
__global__ __launch_bounds__(256) void pack_whh(const float* __restrict__ Whh, float* __restrict__ WhhP){
  int i = blockIdx.x*256 + threadIdx.x;
  if (i >= 64*192) return;
  int j = i / 192, r = i % 192;
  int g = r / 64, k = r % 64;
  WhhP[j*192 + g*64 + k] = Whh[(g*64 + j)*64 + k];
}

// One thread per edge: m = [x[src](9), ea(3)]; h1 = relu(W1 m + b1); msg = W2 h1 + b2;
// atomicAdd into transposed aggT[j*N + dst].
__global__ __launch_bounds__(256) void edge_kernel(
    const float* __restrict__ x, const int* __restrict__ ei, const float* __restrict__ ea,
    const float* __restrict__ W1, const float* __restrict__ b1,
    const float* __restrict__ W2, const float* __restrict__ b2,
    float* __restrict__ aggT, int E, int N)
{
  __shared__ __align__(16) float sW1[64*12];
  __shared__ __align__(16) float sW2[64*64];
  __shared__ float sb1[64], sb2[64];
  for (int i = threadIdx.x; i < 64*12; i += 256) sW1[i] = W1[i];
  for (int i = threadIdx.x; i < 64*64; i += 256) sW2[i] = W2[i];
  if (threadIdx.x < 64){ sb1[threadIdx.x]=b1[threadIdx.x]; sb2[threadIdx.x]=b2[threadIdx.x]; }
  __syncthreads();
  int e = blockIdx.x*256 + threadIdx.x;
  if (e >= E) return;
  int src = ei[e];
  int dst = ei[E + e];
  float m[12];
  #pragma unroll
  for (int i=0;i<9;i++) m[i] = x[src*9+i];
  #pragma unroll
  for (int i=0;i<3;i++) m[9+i] = ea[e*3+i];
  float h1[64];
  #pragma unroll
  for (int j=0;j<64;j++){
    const float4* w = (const float4*)(sW1 + j*12);
    float4 w0=w[0], w1=w[1], w2v=w[2];
    float acc = sb1[j]
      + w0.x*m[0]+w0.y*m[1]+w0.z*m[2]+w0.w*m[3]
      + w1.x*m[4]+w1.y*m[5]+w1.z*m[6]+w1.w*m[7]
      + w2v.x*m[8]+w2v.y*m[9]+w2v.z*m[10]+w2v.w*m[11];
    h1[j] = fmaxf(acc, 0.0f);
  }
  for (int j=0;j<64;j++){
    const float4* w = (const float4*)(sW2 + j*64);
    float acc = sb2[j];
    #pragma unroll
    for (int k4=0;k4<16;k4++){
      float4 wv = w[k4];
      acc += wv.x*h1[4*k4] + wv.y*h1[4*k4+1] + wv.z*h1[4*k4+2] + wv.w*h1[4*k4+3];
    }
    atomicAdd(&aggT[(size_t)j*N + dst], acc);
  }
}

// gi = agg @ Wih.T + bih  -> giT[o*N + node]   (thread per node; Wih natural [192,64] in LDS)
__global__ __launch_bounds__(256) void gi_kernel(
    const float* __restrict__ aggT, const float* __restrict__ Wih, const float* __restrict__ bih,
    float* __restrict__ giT, int N)
{
  __shared__ __align__(16) float sW[192*64];
  __shared__ float sb[192];
  for (int i=threadIdx.x;i<192*64;i+=256) sW[i]=Wih[i];
  for (int i=threadIdx.x;i<192;i+=256) sb[i]=bih[i];
  __syncthreads();
  int node = blockIdx.x*256 + threadIdx.x;
  if (node >= N) return;
  float a[64];
  #pragma unroll
  for (int k=0;k<64;k++) a[k] = aggT[(size_t)k*N + node];
  for (int o=0;o<192;o++){
    const float4* w = (const float4*)(sW + o*64);
    float acc = sb[o];
    #pragma unroll
    for (int k4=0;k4<16;k4++){
      float4 wv = w[k4];
      acc += wv.x*a[4*k4] + wv.y*a[4*k4+1] + wv.z*a[4*k4+2] + wv.w*a[4*k4+3];
    }
    giT[(size_t)o*N + node] = acc;
  }
}

// 6 GRU steps, h[64] in registers; WhhP[j][g][k] in LDS; fused mean-pool numerator via atomics.
__global__ __launch_bounds__(256) void gru_kernel(
    const float* __restrict__ giT, const float* __restrict__ WhhP,
    const float* __restrict__ bhh, const int* __restrict__ batch,
    float* __restrict__ gsum, float* __restrict__ gcnt, int N)
{
  __shared__ __align__(16) float sW[64*192];
  __shared__ float sb[192];
  for (int i=threadIdx.x;i<64*192;i+=256) sW[i]=WhhP[i];
  for (int i=threadIdx.x;i<192;i+=256) sb[i]=bhh[i];
  __syncthreads();
  int node = blockIdx.x*256 + threadIdx.x;
  if (node >= N) return;
  float h[64];
  // step 0: h==0  =>  gh = bhh
  #pragma unroll
  for (int j=0;j<64;j++){
    float ir = giT[(size_t)j*N+node];
    float iz = giT[(size_t)(64+j)*N+node];
    float inn= giT[(size_t)(128+j)*N+node];
    float r = sigmoidf_(ir + sb[j]);
    float z = sigmoidf_(iz + sb[64+j]);
    float n = tanhf(inn + r*sb[128+j]);
    h[j] = (1.0f - z)*n;
  }
  for (int s=1;s<6;s++){
    float hn[64];
    #pragma unroll
    for (int j=0;j<64;j++){
      const float4* wr = (const float4*)(sW + j*192);
      const float4* wz = wr + 16;
      const float4* wn = wr + 32;
      float ar = sb[j], az = sb[64+j], an = sb[128+j];
      #pragma unroll
      for (int k4=0;k4<16;k4++){
        float4 aw = wr[k4], bw = wz[k4], cw = wn[k4];
        float h0=h[4*k4], h1v=h[4*k4+1], h2v=h[4*k4+2], h3v=h[4*k4+3];
        ar += aw.x*h0 + aw.y*h1v + aw.z*h2v + aw.w*h3v;
        az += bw.x*h0 + bw.y*h1v + bw.z*h2v + bw.w*h3v;
        an += cw.x*h0 + cw.y*h1v + cw.z*h2v + cw.w*h3v;
      }
      float ir = giT[(size_t)j*N+node];
      float iz = giT[(size_t)(64+j)*N+node];
      float inn= giT[(size_t)(128+j)*N+node];
      float r = sigmoidf_(ir + ar);
      float z = sigmoidf_(iz + az);
      float n = tanhf(inn + r*an);
      hn[j] = (1.0f - z)*n + z*h[j];
    }
    #pragma unroll
    for (int j=0;j<64;j++) h[j] = hn[j];
  }
  int g = batch[node];
  #pragma unroll
  for (int j=0;j<64;j++) atomicAdd(&gsum[g*64+j], h[j]);
  atomicAdd(&gcnt[g], 1.0f);
}

// Thread per graph: pooled = gsum/count; out = W2 relu(W1 pooled + b1) + b2
__global__ __launch_bounds__(256) void readout_kernel(
  const float* __restrict__ gsum, const float* __restrict__ gcnt,
  const float* __restrict__ W1, const float* __restrict__ b1,
  const float* __restrict__ W2, const float* __restrict__ b2,
  float* __restrict__ out, int G)
{
  __shared__ __align__(16) float sW1[64*64];
  __shared__ float sb1[64], sW2v[64];
  for (int i=threadIdx.x;i<64*64;i+=256) sW1[i]=W1[i];
  if (threadIdx.x<64){ sb1[threadIdx.x]=b1[threadIdx.x]; sW2v[threadIdx.x]=W2[threadIdx.x]; }
  __syncthreads();
  int g = blockIdx.x*256 + threadIdx.x;
  if (g >= G) return;
  float inv = 1.0f / fmaxf(gcnt[g], 1.0f);
  float p[64];
  #pragma unroll
  for (int k=0;k<64;k++) p[k] = gsum[g*64+k]*inv;
  float acc = b2[0];
  for (int j=0;j<64;j++){
    const float4* w = (const float4*)(sW1 + j*64);
    float t = sb1[j];
    #pragma unroll
    for (int k4=0;k4<16;k4++){
      float4 wv=w[k4];
      t += wv.x*p[4*k4]+wv.y*p[4*k4+1]+wv.z*p[4*k4+2]+wv.w*p[4*k4+3];
    }
    acc += sW2v[j]*fmaxf(t,0.0f);
  }
  out[g] = acc;
}

extern "C" void kernel_launch(void* const* d_in, const int* in_sizes, int n_in,
                              void* d_out, int out_size, void* d_ws, size_t ws_size,
                              hipStream_t stream)
{
  const float* x    = (const float*)d_in[0];
  const int*   ei   = (const int*)  d_in[1];
  const float* ea   = (const float*)d_in[2];
  const int*   batch= (const int*)  d_in[3];
  const float* mW1  = (const float*)d_in[4];
  const float* mb1  = (const float*)d_in[5];
  const float* mW2  = (const float*)d_in[6];
  const float* mb2  = (const float*)d_in[7];
  const float* Wih  = (const float*)d_in[8];
  const float* Whh  = (const float*)d_in[9];
  const float* bih  = (const float*)d_in[10];
  const float* bhh  = (const float*)d_in[11];
  const float* rW1  = (const float*)d_in[12];
  const float* rb1  = (const float*)d_in[13];
  const float* rW2  = (const float*)d_in[14];
  const float* rb2  = (const float*)d_in[15];
  float* out = (float*)d_out;

  int N = in_sizes[0] / 9;
  int E = in_sizes[1] / 2;
  int G = out_size;

  float* ws   = (float*)d_ws;
  float* aggT = ws;
  float* giT  = aggT + (size_t)64*N;
  float* WhhP = giT  + (size_t)192*N;
  float* gsum = WhhP + 64*192;
  float* gcnt = gsum + (size_t)64*G;

  hipMemsetAsync(aggT, 0, (size_t)64*N*sizeof(float), stream);
  hipMemsetAsync(gsum, 0, (size_t)(64*G + G)*sizeof(float), stream);

  pack_whh<<<(64*192+255)/256, 256, 0, stream>>>(Whh, WhhP);
  edge_kernel<<<(E+255)/256, 256, 0, stream>>>(x, ei, ea, mW1, mb1, mW2, mb2, aggT, E, N);
  gi_kernel<<<(N+255)/256, 256, 0, stream>>>(aggT, Wih, bih, giT, N);
  gru_kernel<<<(N+255)/256, 256, 0, stream>>>(giT, WhhP, bhh, batch, gsum, gcnt, N);
  readout_kernel<<<(G+255)/256, 256, 0, stream>>>(gsum, gcnt, rW1, rb1, rW2, rb2, out, G);
}

// Round 2
// 1738.693 us; speedup vs baseline: 3.7163x; 3.7163x over previous
//
#include <hip/hip_runtime.h>
#include <math.h>

#define CH 1024

__device__ __forceinline__ float sigmoidf_(float x){ return 1.0f/(1.0f+__expf(-x)); }

// ---------- CSR build ----------
__global__ __launch_bounds__(256) void count_kernel(const int* __restrict__ ei, int* __restrict__ cnt, int E){
  int e = blockIdx.x*256 + threadIdx.x;
  if (e < E) atomicAdd(&cnt[ei[E + e]], 1);
}

__global__ __launch_bounds__(256) void scan_partial(const int* __restrict__ cnt, int* __restrict__ bsum, int N){
  __shared__ int s[256];
  int b = blockIdx.x, t = threadIdx.x;
  int base = b*CH;
  int sum = 0;
  for (int i = t; i < CH; i += 256){ int idx = base + i; sum += (idx < N) ? cnt[idx] : 0; }
  s[t] = sum; __syncthreads();
  for (int off = 128; off > 0; off >>= 1){ if (t < off) s[t] += s[t+off]; __syncthreads(); }
  if (t == 0) bsum[b] = s[0];
}

__global__ void scan_bsum(int* __restrict__ bsum, int B){
  if (threadIdx.x == 0 && blockIdx.x == 0){
    int acc = 0;
    for (int i = 0; i < B; i++){ int v = bsum[i]; bsum[i] = acc; acc += v; }
  }
}

__global__ __launch_bounds__(256) void scan_final(const int* __restrict__ cnt, const int* __restrict__ bsum,
                                                  int* __restrict__ off, int* __restrict__ cur, int N, int E){
  __shared__ int s[256];
  __shared__ int sx[256];
  int b = blockIdx.x, t = threadIdx.x;
  int i0 = b*CH + t*4;
  int v0 = (i0   < N) ? cnt[i0]   : 0;
  int v1 = (i0+1 < N) ? cnt[i0+1] : 0;
  int v2 = (i0+2 < N) ? cnt[i0+2] : 0;
  int v3 = (i0+3 < N) ? cnt[i0+3] : 0;
  s[t] = v0+v1+v2+v3; __syncthreads();
  if (t == 0){ int acc = bsum[b]; for (int i = 0; i < 256; i++){ sx[i] = acc; acc += s[i]; } }
  __syncthreads();
  int acc = sx[t];
  if (i0   < N){ off[i0]   = acc; cur[i0]   = acc; } acc += v0;
  if (i0+1 < N){ off[i0+1] = acc; cur[i0+1] = acc; } acc += v1;
  if (i0+2 < N){ off[i0+2] = acc; cur[i0+2] = acc; } acc += v2;
  if (i0+3 < N){ off[i0+3] = acc; cur[i0+3] = acc; }
  if (b == 0 && t == 0) off[N] = E;
}

__global__ __launch_bounds__(256) void fill_kernel(const int* __restrict__ ei, int* __restrict__ cur,
                                                   int* __restrict__ eids, int E){
  int e = blockIdx.x*256 + threadIdx.x;
  if (e < E){ int p = atomicAdd(&cur[ei[E + e]], 1); eids[p] = e; }
}

// ---------- per-node gather + message MLP ----------
// Wave per node, lane j owns feature j. agg[n][j] = W2 * (sum_e relu(W1 m_e + b1)) + deg*b2.
__global__ __launch_bounds__(256) void node_msg_kernel(
    const float* __restrict__ x, const int* __restrict__ ei, const float* __restrict__ ea,
    const int* __restrict__ off, const int* __restrict__ eids,
    const float* __restrict__ W1, const float* __restrict__ b1,
    const float* __restrict__ W2, const float* __restrict__ b2,
    float* __restrict__ agg, int N, int E)
{
  __shared__ float sW1T[12*64];   // [i][j] = W1[j][i]
  __shared__ float sW2T[64*64];   // [k][j] = W2[j][k]
  __shared__ float sb1[64], sb2[64];
  int t = threadIdx.x;
  for (int i = t; i < 12*64; i += 256){ int ii = i >> 6, j = i & 63; sW1T[i] = W1[j*12 + ii]; }
  for (int i = t; i < 64*64; i += 256){ int k = i >> 6, j = i & 63; sW2T[i] = W2[j*64 + k]; }
  if (t < 64){ sb1[t] = b1[t]; sb2[t] = b2[t]; }
  __syncthreads();
  int lane = t & 63;
  int node = blockIdx.x*4 + (t >> 6);
  if (node >= N) return;
  int s = off[node], e = off[node+1];
  float hsum = 0.0f;
  for (int p = s; p < e; p++){
    int eid = eids[p];
    int src = ei[eid];
    float m[12];
    #pragma unroll
    for (int i = 0; i < 9; i++) m[i] = x[src*9 + i];
    #pragma unroll
    for (int i = 0; i < 3; i++) m[9+i] = ea[eid*3 + i];
    float acc = sb1[lane];
    #pragma unroll
    for (int i = 0; i < 12; i++) acc += sW1T[i*64 + lane] * m[i];
    hsum += fmaxf(acc, 0.0f);
  }
  float accj = (float)(e - s) * sb2[lane];
  #pragma unroll 8
  for (int k = 0; k < 64; k++){
    float hk = __shfl(hsum, k, 64);
    accj += sW2T[k*64 + lane] * hk;
  }
  agg[(size_t)node*64 + lane] = accj;
}

// ---------- gi = agg @ Wih.T + bih  -> giT[o*N + node] ----------
__global__ __launch_bounds__(256) void gi_kernel(
    const float* __restrict__ agg, const float* __restrict__ Wih, const float* __restrict__ bih,
    float* __restrict__ giT, int N)
{
  __shared__ __align__(16) float sW[192*64];
  __shared__ float sb[192];
  for (int i = threadIdx.x; i < 192*64; i += 256) sW[i] = Wih[i];
  for (int i = threadIdx.x; i < 192; i += 256) sb[i] = bih[i];
  __syncthreads();
  int node = blockIdx.x*256 + threadIdx.x;
  if (node >= N) return;
  float a[64];
  const float4* ap = (const float4*)(agg + (size_t)node*64);
  #pragma unroll
  for (int k4 = 0; k4 < 16; k4++){
    float4 v = ap[k4];
    a[4*k4] = v.x; a[4*k4+1] = v.y; a[4*k4+2] = v.z; a[4*k4+3] = v.w;
  }
  for (int o = 0; o < 192; o++){
    const float4* w = (const float4*)(sW + o*64);
    float acc = sb[o];
    #pragma unroll
    for (int k4 = 0; k4 < 16; k4++){
      float4 wv = w[k4];
      acc += wv.x*a[4*k4] + wv.y*a[4*k4+1] + wv.z*a[4*k4+2] + wv.w*a[4*k4+3];
    }
    giT[(size_t)o*N + node] = acc;
  }
}

// Build WhhP[j*192 + g*64 + k] = Whh[(g*64+j)*64 + k]
__global__ __launch_bounds__(256) void pack_whh(const float* __restrict__ Whh, float* __restrict__ WhhP){
  int i = blockIdx.x*256 + threadIdx.x;
  if (i >= 64*192) return;
  int j = i / 192, r = i % 192;
  int g = r / 64, k = r % 64;
  WhhP[j*192 + g*64 + k] = Whh[(g*64 + j)*64 + k];
}

// ---------- 6 GRU steps, h in registers; writes h to hout (coalesced), no atomics ----------
__global__ __launch_bounds__(256) void gru_kernel(
    const float* __restrict__ giT, const float* __restrict__ WhhP,
    const float* __restrict__ bhh, float* __restrict__ hout, int N)
{
  __shared__ __align__(16) float sW[64*192];
  __shared__ float sb[192];
  for (int i = threadIdx.x; i < 64*192; i += 256) sW[i] = WhhP[i];
  for (int i = threadIdx.x; i < 192; i += 256) sb[i] = bhh[i];
  __syncthreads();
  int node = blockIdx.x*256 + threadIdx.x;
  if (node >= N) return;
  float h[64];
  #pragma unroll
  for (int j = 0; j < 64; j++){
    float ir = giT[(size_t)j*N+node];
    float iz = giT[(size_t)(64+j)*N+node];
    float inn= giT[(size_t)(128+j)*N+node];
    float r = sigmoidf_(ir + sb[j]);
    float z = sigmoidf_(iz + sb[64+j]);
    float n = tanhf(inn + r*sb[128+j]);
    h[j] = (1.0f - z)*n;
  }
  for (int st = 1; st < 6; st++){
    float hn[64];
    #pragma unroll
    for (int j = 0; j < 64; j++){
      const float4* wr = (const float4*)(sW + j*192);
      const float4* wz = wr + 16;
      const float4* wn = wr + 32;
      float ar = sb[j], az = sb[64+j], an = sb[128+j];
      #pragma unroll
      for (int k4 = 0; k4 < 16; k4++){
        float4 aw = wr[k4], bw = wz[k4], cw = wn[k4];
        float h0=h[4*k4], h1v=h[4*k4+1], h2v=h[4*k4+2], h3v=h[4*k4+3];
        ar += aw.x*h0 + aw.y*h1v + aw.z*h2v + aw.w*h3v;
        az += bw.x*h0 + bw.y*h1v + bw.z*h2v + bw.w*h3v;
        an += cw.x*h0 + cw.y*h1v + cw.z*h2v + cw.w*h3v;
      }
      float ir = giT[(size_t)j*N+node];
      float iz = giT[(size_t)(64+j)*N+node];
      float inn= giT[(size_t)(128+j)*N+node];
      float r = sigmoidf_(ir + ar);
      float z = sigmoidf_(iz + az);
      float n = tanhf(inn + r*an);
      hn[j] = (1.0f - z)*n + z*h[j];
    }
    #pragma unroll
    for (int j = 0; j < 64; j++) h[j] = hn[j];
  }
  float4* hp = (float4*)(hout + (size_t)node*64);
  #pragma unroll
  for (int q = 0; q < 16; q++) hp[q] = make_float4(h[4*q], h[4*q+1], h[4*q+2], h[4*q+3]);
}

// ---------- graph ranges via binary search on sorted batch ----------
__global__ __launch_bounds__(256) void gstart_kernel(const int* __restrict__ batch, int* __restrict__ gstart, int N, int G){
  int g = blockIdx.x*256 + threadIdx.x;
  if (g > G) return;
  int lo = 0, hi = N;
  while (lo < hi){ int mid = (lo + hi) >> 1; if (batch[mid] < g) lo = mid + 1; else hi = mid; }
  gstart[g] = lo;
}

// wave per graph: mean over the graph's node range
__global__ __launch_bounds__(64) void pool_kernel(const float* __restrict__ hout, const int* __restrict__ gstart,
                                                  float* __restrict__ pooled, int G){
  int g = blockIdx.x; int lane = threadIdx.x;
  int s = gstart[g], e = gstart[g+1];
  float acc = 0.0f;
  for (int n = s; n < e; n++) acc += hout[(size_t)n*64 + lane];
  float c = fmaxf((float)(e - s), 1.0f);
  pooled[g*64 + lane] = acc / c;
}

// thread per graph: out = W2 relu(W1 pooled + b1) + b2
__global__ __launch_bounds__(256) void readout_kernel(
  const float* __restrict__ pooled,
  const float* __restrict__ W1, const float* __restrict__ b1,
  const float* __restrict__ W2, const float* __restrict__ b2,
  float* __restrict__ out, int G)
{
  __shared__ __align__(16) float sW1[64*64];
  __shared__ float sb1[64], sW2v[64];
  for (int i = threadIdx.x; i < 64*64; i += 256) sW1[i] = W1[i];
  if (threadIdx.x < 64){ sb1[threadIdx.x] = b1[threadIdx.x]; sW2v[threadIdx.x] = W2[threadIdx.x]; }
  __syncthreads();
  int g = blockIdx.x*256 + threadIdx.x;
  if (g >= G) return;
  float p[64];
  const float4* pp = (const float4*)(pooled + g*64);
  #pragma unroll
  for (int k4 = 0; k4 < 16; k4++){
    float4 v = pp[k4];
    p[4*k4] = v.x; p[4*k4+1] = v.y; p[4*k4+2] = v.z; p[4*k4+3] = v.w;
  }
  float acc = b2[0];
  for (int j = 0; j < 64; j++){
    const float4* w = (const float4*)(sW1 + j*64);
    float tacc = sb1[j];
    #pragma unroll
    for (int k4 = 0; k4 < 16; k4++){
      float4 wv = w[k4];
      tacc += wv.x*p[4*k4] + wv.y*p[4*k4+1] + wv.z*p[4*k4+2] + wv.w*p[4*k4+3];
    }
    acc += sW2v[j]*fmaxf(tacc, 0.0f);
  }
  out[g] = acc;
}

extern "C" void kernel_launch(void* const* d_in, const int* in_sizes, int n_in,
                              void* d_out, int out_size, void* d_ws, size_t ws_size,
                              hipStream_t stream)
{
  const float* x    = (const float*)d_in[0];
  const int*   ei   = (const int*)  d_in[1];
  const float* ea   = (const float*)d_in[2];
  const int*   batch= (const int*)  d_in[3];
  const float* mW1  = (const float*)d_in[4];
  const float* mb1  = (const float*)d_in[5];
  const float* mW2  = (const float*)d_in[6];
  const float* mb2  = (const float*)d_in[7];
  const float* Wih  = (const float*)d_in[8];
  const float* Whh  = (const float*)d_in[9];
  const float* bih  = (const float*)d_in[10];
  const float* bhh  = (const float*)d_in[11];
  const float* rW1  = (const float*)d_in[12];
  const float* rb1  = (const float*)d_in[13];
  const float* rW2  = (const float*)d_in[14];
  const float* rb2  = (const float*)d_in[15];
  float* out = (float*)d_out;

  int N = in_sizes[0] / 9;
  int E = in_sizes[1] / 2;
  int G = out_size;

  // workspace layout: floats first (16B-aligned blocks), then ints
  float* fws   = (float*)d_ws;
  float* agg   = fws;                       // 64N floats (reused as hout after gi)
  float* giT   = agg  + (size_t)64*N;       // 192N floats
  float* WhhP  = giT  + (size_t)192*N;      // 12288 floats
  float* pooled= WhhP + 64*192;             // 64G floats
  int*   iws   = (int*)(pooled + (size_t)64*G);
  int*   cnt   = iws;                       // N
  int*   off   = cnt + N;                   // N+1
  int*   cur   = off + N + 1;               // N
  int*   bsum  = cur + N;                   // up to 1024
  int*   eids  = bsum + 1024;               // E
  int*   gstart= eids + E;                  // G+1

  int B1 = (N + CH - 1) / CH;

  hipMemsetAsync(cnt, 0, (size_t)N*sizeof(int), stream);

  count_kernel<<<(E+255)/256, 256, 0, stream>>>(ei, cnt, E);
  scan_partial<<<B1, 256, 0, stream>>>(cnt, bsum, N);
  scan_bsum<<<1, 64, 0, stream>>>(bsum, B1);
  scan_final<<<B1, 256, 0, stream>>>(cnt, bsum, off, cur, N, E);
  fill_kernel<<<(E+255)/256, 256, 0, stream>>>(ei, cur, eids, E);

  pack_whh<<<(64*192+255)/256, 256, 0, stream>>>(Whh, WhhP);

  node_msg_kernel<<<(N+3)/4, 256, 0, stream>>>(x, ei, ea, off, eids, mW1, mb1, mW2, mb2, agg, N, E);
  gi_kernel<<<(N+255)/256, 256, 0, stream>>>(agg, Wih, bih, giT, N);
  gru_kernel<<<(N+255)/256, 256, 0, stream>>>(giT, WhhP, bhh, /*hout=*/agg, N);

  gstart_kernel<<<(G+256)/256, 256, 0, stream>>>(batch, gstart, N, G);
  pool_kernel<<<G, 64, 0, stream>>>(agg, gstart, pooled, G);
  readout_kernel<<<(G+255)/256, 256, 0, stream>>>(pooled, rW1, rb1, rW2, rb2, out, G);
}

// Round 3
// 905.950 us; speedup vs baseline: 7.1323x; 1.9192x over previous
//
#include <hip/hip_runtime.h>
#include <math.h>

#define CH 1024

__device__ __forceinline__ float sigmoidf_(float x){ return 1.0f/(1.0f+__expf(-x)); }
__device__ __forceinline__ float tanhf_(float x){ return 1.0f - 2.0f/(1.0f+__expf(2.0f*x)); }
__device__ __forceinline__ float bcast(float v, int k){
  return __uint_as_float(__builtin_amdgcn_readlane(__float_as_uint(v), k));
}

// ---------- CSR build ----------
__global__ __launch_bounds__(256) void count_kernel(const int* __restrict__ ei, int* __restrict__ cnt, int E){
  int e = blockIdx.x*256 + threadIdx.x;
  if (e < E) atomicAdd(&cnt[ei[E + e]], 1);
}

__global__ __launch_bounds__(256) void scan_partial(const int* __restrict__ cnt, int* __restrict__ bsum, int N){
  __shared__ int s[256];
  int b = blockIdx.x, t = threadIdx.x;
  int base = b*CH;
  int sum = 0;
  for (int i = t; i < CH; i += 256){ int idx = base + i; sum += (idx < N) ? cnt[idx] : 0; }
  s[t] = sum; __syncthreads();
  for (int off = 128; off > 0; off >>= 1){ if (t < off) s[t] += s[t+off]; __syncthreads(); }
  if (t == 0) bsum[b] = s[0];
}

__global__ void scan_bsum(int* __restrict__ bsum, int B){
  if (threadIdx.x == 0 && blockIdx.x == 0){
    int acc = 0;
    for (int i = 0; i < B; i++){ int v = bsum[i]; bsum[i] = acc; acc += v; }
  }
}

__global__ __launch_bounds__(256) void scan_final(const int* __restrict__ cnt, const int* __restrict__ bsum,
                                                  int* __restrict__ off, int* __restrict__ cur, int N, int E){
  __shared__ int s[256];
  __shared__ int sx[256];
  int b = blockIdx.x, t = threadIdx.x;
  int i0 = b*CH + t*4;
  int v0 = (i0   < N) ? cnt[i0]   : 0;
  int v1 = (i0+1 < N) ? cnt[i0+1] : 0;
  int v2 = (i0+2 < N) ? cnt[i0+2] : 0;
  int v3 = (i0+3 < N) ? cnt[i0+3] : 0;
  s[t] = v0+v1+v2+v3; __syncthreads();
  if (t == 0){ int acc = bsum[b]; for (int i = 0; i < 256; i++){ sx[i] = acc; acc += s[i]; } }
  __syncthreads();
  int acc = sx[t];
  if (i0   < N){ off[i0]   = acc; cur[i0]   = acc; } acc += v0;
  if (i0+1 < N){ off[i0+1] = acc; cur[i0+1] = acc; } acc += v1;
  if (i0+2 < N){ off[i0+2] = acc; cur[i0+2] = acc; } acc += v2;
  if (i0+3 < N){ off[i0+3] = acc; cur[i0+3] = acc; }
  if (b == 0 && t == 0) off[N] = E;
}

// fill packed CSR: csr[p] = (as_float(src), ea0, ea1, ea2)
__global__ __launch_bounds__(256) void fill_kernel(const int* __restrict__ ei, const float* __restrict__ ea,
                                                   int* __restrict__ cur, float4* __restrict__ csr, int E){
  int e = blockIdx.x*256 + threadIdx.x;
  if (e < E){
    int p = atomicAdd(&cur[ei[E + e]], 1);
    csr[p] = make_float4(__int_as_float(ei[e]), ea[e*3], ea[e*3+1], ea[e*3+2]);
  }
}

// pack a [192][64] gate matrix W into P[g][k][j] = W[g*64+j][k]  (12288 elems)
__global__ __launch_bounds__(256) void pack3(const float* __restrict__ W, float* __restrict__ P){
  int i = blockIdx.x*256 + threadIdx.x;
  if (i >= 3*64*64) return;
  int g = i >> 12, r = i & 4095;
  int k = r >> 6, j = r & 63;
  P[i] = W[(g*64 + j)*64 + k];
}

// ---------- per-node gather + message MLP (wave per node, weights in registers) ----------
__global__ __launch_bounds__(256, 2) void node_msg_kernel(
    const float* __restrict__ x, const float4* __restrict__ csr, const int* __restrict__ off,
    const float* __restrict__ W1, const float* __restrict__ b1,
    const float* __restrict__ W2, const float* __restrict__ b2,
    float* __restrict__ agg, int N)
{
  int t = threadIdx.x; int lane = t & 63;
  float w1[12], w2[64];
  #pragma unroll
  for (int i = 0; i < 12; i++) w1[i] = W1[lane*12 + i];
  #pragma unroll
  for (int k = 0; k < 64; k++) w2[k] = W2[lane*64 + k];
  float bb1 = b1[lane], bb2 = b2[lane];
  int wid = (blockIdx.x*256 + t) >> 6;
  int nw = gridDim.x*4;
  for (int node = wid; node < N; node += nw){
    int s = off[node], e = off[node+1];
    float hsum = 0.0f;
    for (int p = s; p < e; p++){
      float4 c = csr[p];
      int src = __float_as_int(c.x);
      const float* xr = x + (size_t)src*9;
      float acc = bb1;
      acc += w1[0]*xr[0] + w1[1]*xr[1] + w1[2]*xr[2];
      acc += w1[3]*xr[3] + w1[4]*xr[4] + w1[5]*xr[5];
      acc += w1[6]*xr[6] + w1[7]*xr[7] + w1[8]*xr[8];
      acc += w1[9]*c.y + w1[10]*c.z + w1[11]*c.w;
      hsum += fmaxf(acc, 0.0f);
    }
    float accj = (float)(e - s) * bb2;
    #pragma unroll
    for (int k = 0; k < 64; k++){
      float hk = bcast(hsum, k);
      accj += w2[k]*hk;
    }
    agg[(size_t)node*64 + lane] = accj;
  }
}

// ---------- gi[node][192] = agg @ Wih.T + bih (wave per node, Wih in registers) ----------
__global__ __launch_bounds__(256, 2) void gi_kernel(
    const float* __restrict__ agg, const float* __restrict__ WihP, const float* __restrict__ bih,
    float* __restrict__ gi, int N)
{
  int t = threadIdx.x; int lane = t & 63;
  float wr[64], wz[64], wn[64];
  #pragma unroll
  for (int k = 0; k < 64; k++){
    wr[k] = WihP[k*64 + lane];
    wz[k] = WihP[4096 + k*64 + lane];
    wn[k] = WihP[8192 + k*64 + lane];
  }
  float br = bih[lane], bz = bih[64+lane], bn = bih[128+lane];
  int wid = (blockIdx.x*256 + t) >> 6;
  int nw = gridDim.x*4;
  for (int node = wid; node < N; node += nw){
    float a = agg[(size_t)node*64 + lane];
    float ar = br, az = bz, an = bn;
    #pragma unroll
    for (int k = 0; k < 64; k++){
      float ak = bcast(a, k);
      ar += wr[k]*ak; az += wz[k]*ak; an += wn[k]*ak;
    }
    size_t base = (size_t)node*192;
    gi[base + lane] = ar;
    gi[base + 64 + lane] = az;
    gi[base + 128 + lane] = an;
  }
}

// ---------- 6 GRU steps (wave per node, Whh in registers, h = 1 reg/lane) ----------
__global__ __launch_bounds__(256, 2) void gru_kernel(
    const float* __restrict__ gi, const float* __restrict__ WhhP, const float* __restrict__ bhh,
    float* __restrict__ hout, int N)
{
  int t = threadIdx.x; int lane = t & 63;
  float wr[64], wz[64], wn[64];
  #pragma unroll
  for (int k = 0; k < 64; k++){
    wr[k] = WhhP[k*64 + lane];
    wz[k] = WhhP[4096 + k*64 + lane];
    wn[k] = WhhP[8192 + k*64 + lane];
  }
  float br = bhh[lane], bz = bhh[64+lane], bn = bhh[128+lane];
  int wid = (blockIdx.x*256 + t) >> 6;
  int nw = gridDim.x*4;
  for (int node = wid; node < N; node += nw){
    size_t base = (size_t)node*192;
    float gr = gi[base + lane];
    float gz = gi[base + 64 + lane];
    float gn = gi[base + 128 + lane];
    // step 0 (h == 0)
    float r = sigmoidf_(gr + br);
    float z = sigmoidf_(gz + bz);
    float n = tanhf_(gn + r*bn);
    float h = (1.0f - z)*n;
    for (int st = 1; st < 6; st++){
      float ar = br, az = bz, an = bn;
      #pragma unroll
      for (int k = 0; k < 64; k++){
        float hk = bcast(h, k);
        ar += wr[k]*hk; az += wz[k]*hk; an += wn[k]*hk;
      }
      float r2 = sigmoidf_(gr + ar);
      float z2 = sigmoidf_(gz + az);
      float n2 = tanhf_(gn + r2*an);
      h = (1.0f - z2)*n2 + z2*h;
    }
    hout[(size_t)node*64 + lane] = h;
  }
}

// ---------- graph ranges via binary search on sorted batch ----------
__global__ __launch_bounds__(256) void gstart_kernel(const int* __restrict__ batch, int* __restrict__ gstart, int N, int G){
  int g = blockIdx.x*256 + threadIdx.x;
  if (g > G) return;
  int lo = 0, hi = N;
  while (lo < hi){ int mid = (lo + hi) >> 1; if (batch[mid] < g) lo = mid + 1; else hi = mid; }
  gstart[g] = lo;
}

// wave per graph: mean over the graph's node range
__global__ __launch_bounds__(64) void pool_kernel(const float* __restrict__ hout, const int* __restrict__ gstart,
                                                  float* __restrict__ pooled, int G){
  int g = blockIdx.x; int lane = threadIdx.x;
  int s = gstart[g], e = gstart[g+1];
  float acc = 0.0f;
  for (int n = s; n < e; n++) acc += hout[(size_t)n*64 + lane];
  float c = fmaxf((float)(e - s), 1.0f);
  pooled[g*64 + lane] = acc / c;
}

// thread per graph: out = W2 relu(W1 pooled + b1) + b2
__global__ __launch_bounds__(256) void readout_kernel(
  const float* __restrict__ pooled,
  const float* __restrict__ W1, const float* __restrict__ b1,
  const float* __restrict__ W2, const float* __restrict__ b2,
  float* __restrict__ out, int G)
{
  __shared__ __align__(16) float sW1[64*64];
  __shared__ float sb1[64], sW2v[64];
  for (int i = threadIdx.x; i < 64*64; i += 256) sW1[i] = W1[i];
  if (threadIdx.x < 64){ sb1[threadIdx.x] = b1[threadIdx.x]; sW2v[threadIdx.x] = W2[threadIdx.x]; }
  __syncthreads();
  int g = blockIdx.x*256 + threadIdx.x;
  if (g >= G) return;
  float p[64];
  const float4* pp = (const float4*)(pooled + g*64);
  #pragma unroll
  for (int k4 = 0; k4 < 16; k4++){
    float4 v = pp[k4];
    p[4*k4] = v.x; p[4*k4+1] = v.y; p[4*k4+2] = v.z; p[4*k4+3] = v.w;
  }
  float acc = b2[0];
  for (int j = 0; j < 64; j++){
    const float4* w = (const float4*)(sW1 + j*64);
    float tacc = sb1[j];
    #pragma unroll
    for (int k4 = 0; k4 < 16; k4++){
      float4 wv = w[k4];
      tacc += wv.x*p[4*k4] + wv.y*p[4*k4+1] + wv.z*p[4*k4+2] + wv.w*p[4*k4+3];
    }
    acc += sW2v[j]*fmaxf(tacc, 0.0f);
  }
  out[g] = acc;
}

extern "C" void kernel_launch(void* const* d_in, const int* in_sizes, int n_in,
                              void* d_out, int out_size, void* d_ws, size_t ws_size,
                              hipStream_t stream)
{
  const float* x    = (const float*)d_in[0];
  const int*   ei   = (const int*)  d_in[1];
  const float* ea   = (const float*)d_in[2];
  const int*   batch= (const int*)  d_in[3];
  const float* mW1  = (const float*)d_in[4];
  const float* mb1  = (const float*)d_in[5];
  const float* mW2  = (const float*)d_in[6];
  const float* mb2  = (const float*)d_in[7];
  const float* Wih  = (const float*)d_in[8];
  const float* Whh  = (const float*)d_in[9];
  const float* bih  = (const float*)d_in[10];
  const float* bhh  = (const float*)d_in[11];
  const float* rW1  = (const float*)d_in[12];
  const float* rb1  = (const float*)d_in[13];
  const float* rW2  = (const float*)d_in[14];
  const float* rb2  = (const float*)d_in[15];
  float* out = (float*)d_out;

  int N = in_sizes[0] / 9;
  int E = in_sizes[1] / 2;
  int G = out_size;

  // float workspace; csr (4E floats) aliases the gi region (192N floats, 192N >= 4E here)
  float* fws   = (float*)d_ws;
  float* agg   = fws;                        // 64N  (reused as hout by gru)
  float* gi    = agg + (size_t)64*N;         // 192N
  float4* csr  = (float4*)gi;                // 4E floats, dead after node_msg
  float* WhhP  = gi + (size_t)192*N;         // 12288
  float* WihP  = WhhP + 12288;               // 12288
  float* pooled= WihP + 12288;               // 64G
  int*   iws   = (int*)(pooled + (size_t)64*G);
  int*   cnt   = iws;                        // N
  int*   off   = cnt + N;                    // N+1
  int*   cur   = off + N + 1;                // N
  int*   bsum  = cur + N;                    // up to 1024
  int*   gstart= bsum + 1024;                // G+1

  int B1 = (N + CH - 1) / CH;

  hipMemsetAsync(cnt, 0, (size_t)N*sizeof(int), stream);

  count_kernel<<<(E+255)/256, 256, 0, stream>>>(ei, cnt, E);
  scan_partial<<<B1, 256, 0, stream>>>(cnt, bsum, N);
  scan_bsum<<<1, 64, 0, stream>>>(bsum, B1);
  scan_final<<<B1, 256, 0, stream>>>(cnt, bsum, off, cur, N, E);
  fill_kernel<<<(E+255)/256, 256, 0, stream>>>(ei, ea, cur, csr, E);

  pack3<<<48, 256, 0, stream>>>(Whh, WhhP);
  pack3<<<48, 256, 0, stream>>>(Wih, WihP);

  node_msg_kernel<<<1024, 256, 0, stream>>>(x, csr, off, mW1, mb1, mW2, mb2, agg, N);
  gi_kernel<<<512, 256, 0, stream>>>(agg, WihP, bih, gi, N);
  gru_kernel<<<512, 256, 0, stream>>>(gi, WhhP, bhh, /*hout=*/agg, N);

  gstart_kernel<<<(G+256)/256, 256, 0, stream>>>(batch, gstart, N, G);
  pool_kernel<<<G, 64, 0, stream>>>(agg, gstart, pooled, G);
  readout_kernel<<<(G+255)/256, 256, 0, stream>>>(pooled, rW1, rb1, rW2, rb2, out, G);
}

// Round 4
// 665.518 us; speedup vs baseline: 9.7090x; 1.3613x over previous
//
#include <hip/hip_runtime.h>
#include <math.h>

#define CH 1024

typedef __attribute__((ext_vector_type(8))) short bf16x8;
typedef __attribute__((ext_vector_type(4))) float f32x4;

__device__ __forceinline__ float sigmoidf_(float x){ return 1.0f/(1.0f+__expf(-x)); }
__device__ __forceinline__ float tanhf_(float x){ return 1.0f - 2.0f/(1.0f+__expf(2.0f*x)); }
__device__ __forceinline__ unsigned short f2bf(float f){
  union{float f;unsigned u;}v; v.f=f;
  unsigned r = v.u + 0x7fffu + ((v.u>>16)&1u);
  return (unsigned short)(r>>16);
}
__device__ __forceinline__ float bcast(float v, int k){
  return __uint_as_float(__builtin_amdgcn_readlane(__float_as_uint(v), k));
}

// ---------- CSR build ----------
__global__ __launch_bounds__(256) void count_kernel(const int* __restrict__ ei, int* __restrict__ cnt, int E){
  int e = blockIdx.x*256 + threadIdx.x;
  if (e < E) atomicAdd(&cnt[ei[E + e]], 1);
}

__global__ __launch_bounds__(256) void scan_partial(const int* __restrict__ cnt, int* __restrict__ bsum, int N){
  __shared__ int s[256];
  int b = blockIdx.x, t = threadIdx.x;
  int base = b*CH;
  int sum = 0;
  for (int i = t; i < CH; i += 256){ int idx = base + i; sum += (idx < N) ? cnt[idx] : 0; }
  s[t] = sum; __syncthreads();
  for (int off = 128; off > 0; off >>= 1){ if (t < off) s[t] += s[t+off]; __syncthreads(); }
  if (t == 0) bsum[b] = s[0];
}

__global__ void scan_bsum(int* __restrict__ bsum, int B){
  if (threadIdx.x == 0 && blockIdx.x == 0){
    int acc = 0;
    for (int i = 0; i < B; i++){ int v = bsum[i]; bsum[i] = acc; acc += v; }
  }
}

__global__ __launch_bounds__(256) void scan_final(const int* __restrict__ cnt, const int* __restrict__ bsum,
                                                  int* __restrict__ off, int* __restrict__ cur, int N, int E){
  __shared__ int s[256];
  __shared__ int sx[256];
  int b = blockIdx.x, t = threadIdx.x;
  int i0 = b*CH + t*4;
  int v0 = (i0   < N) ? cnt[i0]   : 0;
  int v1 = (i0+1 < N) ? cnt[i0+1] : 0;
  int v2 = (i0+2 < N) ? cnt[i0+2] : 0;
  int v3 = (i0+3 < N) ? cnt[i0+3] : 0;
  s[t] = v0+v1+v2+v3; __syncthreads();
  if (t == 0){ int acc = bsum[b]; for (int i = 0; i < 256; i++){ sx[i] = acc; acc += s[i]; } }
  __syncthreads();
  int acc = sx[t];
  if (i0   < N){ off[i0]   = acc; cur[i0]   = acc; } acc += v0;
  if (i0+1 < N){ off[i0+1] = acc; cur[i0+1] = acc; } acc += v1;
  if (i0+2 < N){ off[i0+2] = acc; cur[i0+2] = acc; } acc += v2;
  if (i0+3 < N){ off[i0+3] = acc; cur[i0+3] = acc; }
  if (b == 0 && t == 0) off[N] = E;
}

// fill packed CSR: csr[p] = (as_float(src), ea0, ea1, ea2)
__global__ __launch_bounds__(256) void fill_kernel(const int* __restrict__ ei, const float* __restrict__ ea,
                                                   int* __restrict__ cur, float4* __restrict__ csr, int E){
  int e = blockIdx.x*256 + threadIdx.x;
  if (e < E){
    int p = atomicAdd(&cur[ei[E + e]], 1);
    csr[p] = make_float4(__int_as_float(ei[e]), ea[e*3], ea[e*3+1], ea[e*3+2]);
  }
}

// pack a [192][64] gate matrix (natural [n][k]) into bf16 B-fragments:
// P[((c*2+kh)*64 + lane)*8 + j] = bf16(W[(c*16 + (lane&15))*64 + kh*32 + 8*(lane>>4) + j])
__global__ __launch_bounds__(256) void pack_frag(const float* __restrict__ W, unsigned short* __restrict__ P){
  int o = blockIdx.x*256 + threadIdx.x;
  if (o >= 12288) return;
  int j = o & 7, l = (o>>3)&63, kh = (o>>9)&1, c = o>>10;
  P[o] = f2bf(W[(c*16 + (l&15))*64 + kh*32 + 8*(l>>4) + j]);
}

// ---------- per-node gather + message MLP (wave per node, weights in registers) ----------
__global__ __launch_bounds__(256, 2) void node_msg_kernel(
    const float* __restrict__ x, const float4* __restrict__ csr, const int* __restrict__ off,
    const float* __restrict__ W1, const float* __restrict__ b1,
    const float* __restrict__ W2, const float* __restrict__ b2,
    float* __restrict__ agg, int N)
{
  int t = threadIdx.x; int lane = t & 63;
  float w1[12], w2[64];
  #pragma unroll
  for (int i = 0; i < 12; i++) w1[i] = W1[lane*12 + i];
  #pragma unroll
  for (int k = 0; k < 64; k++) w2[k] = W2[lane*64 + k];
  float bb1 = b1[lane], bb2 = b2[lane];
  int wid = (blockIdx.x*256 + t) >> 6;
  int nw = gridDim.x*4;
  for (int node = wid; node < N; node += nw){
    int s = off[node], e = off[node+1];
    float hsum = 0.0f;
    for (int p = s; p < e; p++){
      float4 c = csr[p];
      int src = __float_as_int(c.x);
      const float* xr = x + (size_t)src*9;
      float acc = bb1;
      acc += w1[0]*xr[0] + w1[1]*xr[1] + w1[2]*xr[2];
      acc += w1[3]*xr[3] + w1[4]*xr[4] + w1[5]*xr[5];
      acc += w1[6]*xr[6] + w1[7]*xr[7] + w1[8]*xr[8];
      acc += w1[9]*c.y + w1[10]*c.z + w1[11]*c.w;
      hsum += fmaxf(acc, 0.0f);
    }
    float accj = (float)(e - s) * bb2;
    #pragma unroll
    for (int k = 0; k < 64; k++){
      float hk = bcast(hsum, k);
      accj += w2[k]*hk;
    }
    agg[(size_t)node*64 + lane] = accj;
  }
}

// ---------- fused gi + 6-step GRU on matrix cores (16-node tiles, bf16 MFMA) ----------
__global__ __launch_bounds__(256, 2) void gru_mfma(
    float* aggh,   // in: agg [N][64]; out: h [N][64] (same buffer, per-tile in-place)
    const unsigned short* __restrict__ WihF, const unsigned short* __restrict__ WhhF,
    const float* __restrict__ bih, const float* __restrict__ bhh, int N)
{
  __shared__ unsigned short hbuf[4][1024];
  int t = threadIdx.x, lane = t & 63, w = t >> 6;
  int s_ = lane & 15, g_ = lane >> 4;
  unsigned short* hb = hbuf[w];

  const bf16x8* WhhV = (const bf16x8*)WhhF;
  const bf16x8* WihV = (const bf16x8*)WihF;
  bf16x8 whhf[24];
  #pragma unroll
  for (int i = 0; i < 24; i++) whhf[i] = WhhV[i*64 + lane];
  float bi[12], bh[12];
  #pragma unroll
  for (int c = 0; c < 12; c++){ bi[c] = bih[c*16 + s_]; bh[c] = bhh[c*16 + s_]; }

  int wid = (blockIdx.x*256 + t) >> 6;
  int nw = gridDim.x*4;
  int NT = (N + 15) >> 4;
  for (int tile = wid; tile < NT; tile += nw){
    // ---- A-fragments of agg tile (16 nodes x 64 feats) ----
    int nodeA = tile*16 + s_; if (nodeA > N-1) nodeA = N-1;
    const float* ab = aggh + (size_t)nodeA*64 + g_*8;
    float4 v0 = *(const float4*)(ab);
    float4 v1 = *(const float4*)(ab+4);
    float4 v2 = *(const float4*)(ab+32);
    float4 v3 = *(const float4*)(ab+36);
    bf16x8 a0, a1;
    a0[0]=(short)f2bf(v0.x); a0[1]=(short)f2bf(v0.y); a0[2]=(short)f2bf(v0.z); a0[3]=(short)f2bf(v0.w);
    a0[4]=(short)f2bf(v1.x); a0[5]=(short)f2bf(v1.y); a0[6]=(short)f2bf(v1.z); a0[7]=(short)f2bf(v1.w);
    a1[0]=(short)f2bf(v2.x); a1[1]=(short)f2bf(v2.y); a1[2]=(short)f2bf(v2.z); a1[3]=(short)f2bf(v2.w);
    a1[4]=(short)f2bf(v3.x); a1[5]=(short)f2bf(v3.y); a1[6]=(short)f2bf(v3.z); a1[7]=(short)f2bf(v3.w);

    // ---- gi = agg @ Wih.T + bih, kept in registers (12 n-tiles x f32x4) ----
    f32x4 gia[12];
    #pragma unroll
    for (int c = 0; c < 12; c++){
      f32x4 acc; acc[0]=bi[c]; acc[1]=bi[c]; acc[2]=bi[c]; acc[3]=bi[c];
      acc = __builtin_amdgcn_mfma_f32_16x16x32_bf16(a0, WihV[(c*2+0)*64 + lane], acc, 0, 0, 0);
      acc = __builtin_amdgcn_mfma_f32_16x16x32_bf16(a1, WihV[(c*2+1)*64 + lane], acc, 0, 0, 0);
      gia[c] = acc;
    }

    // ---- 6 GRU steps ----
    f32x4 hD[4];
    #pragma unroll
    for (int c = 0; c < 4; c++){ hD[c][0]=0.f; hD[c][1]=0.f; hD[c][2]=0.f; hD[c][3]=0.f; }
    bf16x8 h0 = {0,0,0,0,0,0,0,0};
    bf16x8 h1 = {0,0,0,0,0,0,0,0};
    for (int st = 0; st < 6; st++){
      #pragma unroll
      for (int c = 0; c < 4; c++){
        f32x4 aR, aZ, aN;
        aR[0]=bh[c];   aR[1]=bh[c];   aR[2]=bh[c];   aR[3]=bh[c];
        aZ[0]=bh[4+c]; aZ[1]=bh[4+c]; aZ[2]=bh[4+c]; aZ[3]=bh[4+c];
        aN[0]=bh[8+c]; aN[1]=bh[8+c]; aN[2]=bh[8+c]; aN[3]=bh[8+c];
        aR = __builtin_amdgcn_mfma_f32_16x16x32_bf16(h0, whhf[c*2],       aR, 0,0,0);
        aR = __builtin_amdgcn_mfma_f32_16x16x32_bf16(h1, whhf[c*2+1],     aR, 0,0,0);
        aZ = __builtin_amdgcn_mfma_f32_16x16x32_bf16(h0, whhf[(4+c)*2],   aZ, 0,0,0);
        aZ = __builtin_amdgcn_mfma_f32_16x16x32_bf16(h1, whhf[(4+c)*2+1], aZ, 0,0,0);
        aN = __builtin_amdgcn_mfma_f32_16x16x32_bf16(h0, whhf[(8+c)*2],   aN, 0,0,0);
        aN = __builtin_amdgcn_mfma_f32_16x16x32_bf16(h1, whhf[(8+c)*2+1], aN, 0,0,0);
        #pragma unroll
        for (int r = 0; r < 4; r++){
          float rr = sigmoidf_(gia[c][r]   + aR[r]);
          float zz = sigmoidf_(gia[4+c][r] + aZ[r]);
          float nn = tanhf_(gia[8+c][r] + rr*aN[r]);
          hD[c][r] = (1.0f - zz)*nn + zz*hD[c][r];
        }
      }
      if (st < 5){
        // D-layout -> LDS (bf16, XOR-swizzled) -> A-layout fragments; same-wave only.
        #pragma unroll
        for (int c = 0; c < 4; c++){
          #pragma unroll
          for (int r = 0; r < 4; r++){
            int nl = 4*g_ + r;
            int idx = (nl*64 + 16*c + s_) ^ ((nl & 7) << 3);
            hb[idx] = f2bf(hD[c][r]);
          }
        }
        int r0 = (s_*64 +      8*g_) ^ ((s_ & 7) << 3);
        int r1 = (s_*64 + 32 + 8*g_) ^ ((s_ & 7) << 3);
        h0 = *(const bf16x8*)(hb + r0);
        h1 = *(const bf16x8*)(hb + r1);
      }
    }
    // ---- store h (overwrites this tile's agg rows; tiles are disjoint) ----
    #pragma unroll
    for (int c = 0; c < 4; c++){
      #pragma unroll
      for (int r = 0; r < 4; r++){
        int node = tile*16 + 4*g_ + r;
        if (node < N) aggh[(size_t)node*64 + 16*c + s_] = hD[c][r];
      }
    }
  }
}

// ---------- graph ranges via binary search on sorted batch ----------
__global__ __launch_bounds__(256) void gstart_kernel(const int* __restrict__ batch, int* __restrict__ gstart, int N, int G){
  int g = blockIdx.x*256 + threadIdx.x;
  if (g > G) return;
  int lo = 0, hi = N;
  while (lo < hi){ int mid = (lo + hi) >> 1; if (batch[mid] < g) lo = mid + 1; else hi = mid; }
  gstart[g] = lo;
}

// wave per graph: mean over the graph's node range
__global__ __launch_bounds__(64) void pool_kernel(const float* __restrict__ hout, const int* __restrict__ gstart,
                                                  float* __restrict__ pooled, int G){
  int g = blockIdx.x; int lane = threadIdx.x;
  int s = gstart[g], e = gstart[g+1];
  float acc = 0.0f;
  for (int n = s; n < e; n++) acc += hout[(size_t)n*64 + lane];
  float c = fmaxf((float)(e - s), 1.0f);
  pooled[g*64 + lane] = acc / c;
}

// thread per graph: out = W2 relu(W1 pooled + b1) + b2
__global__ __launch_bounds__(256) void readout_kernel(
  const float* __restrict__ pooled,
  const float* __restrict__ W1, const float* __restrict__ b1,
  const float* __restrict__ W2, const float* __restrict__ b2,
  float* __restrict__ out, int G)
{
  __shared__ __align__(16) float sW1[64*64];
  __shared__ float sb1[64], sW2v[64];
  for (int i = threadIdx.x; i < 64*64; i += 256) sW1[i] = W1[i];
  if (threadIdx.x < 64){ sb1[threadIdx.x] = b1[threadIdx.x]; sW2v[threadIdx.x] = W2[threadIdx.x]; }
  __syncthreads();
  int g = blockIdx.x*256 + threadIdx.x;
  if (g >= G) return;
  float p[64];
  const float4* pp = (const float4*)(pooled + g*64);
  #pragma unroll
  for (int k4 = 0; k4 < 16; k4++){
    float4 v = pp[k4];
    p[4*k4] = v.x; p[4*k4+1] = v.y; p[4*k4+2] = v.z; p[4*k4+3] = v.w;
  }
  float acc = b2[0];
  for (int j = 0; j < 64; j++){
    const float4* wv4 = (const float4*)(sW1 + j*64);
    float tacc = sb1[j];
    #pragma unroll
    for (int k4 = 0; k4 < 16; k4++){
      float4 wv = wv4[k4];
      tacc += wv.x*p[4*k4] + wv.y*p[4*k4+1] + wv.z*p[4*k4+2] + wv.w*p[4*k4+3];
    }
    acc += sW2v[j]*fmaxf(tacc, 0.0f);
  }
  out[g] = acc;
}

extern "C" void kernel_launch(void* const* d_in, const int* in_sizes, int n_in,
                              void* d_out, int out_size, void* d_ws, size_t ws_size,
                              hipStream_t stream)
{
  const float* x    = (const float*)d_in[0];
  const int*   ei   = (const int*)  d_in[1];
  const float* ea   = (const float*)d_in[2];
  const int*   batch= (const int*)  d_in[3];
  const float* mW1  = (const float*)d_in[4];
  const float* mb1  = (const float*)d_in[5];
  const float* mW2  = (const float*)d_in[6];
  const float* mb2  = (const float*)d_in[7];
  const float* Wih  = (const float*)d_in[8];
  const float* Whh  = (const float*)d_in[9];
  const float* bih  = (const float*)d_in[10];
  const float* bhh  = (const float*)d_in[11];
  const float* rW1  = (const float*)d_in[12];
  const float* rb1  = (const float*)d_in[13];
  const float* rW2  = (const float*)d_in[14];
  const float* rb2  = (const float*)d_in[15];
  float* out = (float*)d_out;

  int N = in_sizes[0] / 9;
  int E = in_sizes[1] / 2;
  int G = out_size;

  float* fws   = (float*)d_ws;
  float* agg   = fws;                         // 64N floats (in: agg, out: h)
  float* csrf  = agg + (size_t)64*N;          // 4E floats
  unsigned short* WihF = (unsigned short*)(csrf + (size_t)4*E);  // 12288 ushort
  unsigned short* WhhF = WihF + 12288;                            // 12288 ushort
  float* pooled= (float*)(WhhF + 12288);      // 64G floats
  int*   iws   = (int*)(pooled + (size_t)64*G);
  int*   cnt   = iws;                         // N
  int*   off   = cnt + N;                     // N+1
  int*   cur   = off + N + 1;                 // N
  int*   bsum  = cur + N;                     // up to 1024
  int*   gstart= bsum + 1024;                 // G+1
  float4* csr  = (float4*)csrf;

  int B1 = (N + CH - 1) / CH;

  hipMemsetAsync(cnt, 0, (size_t)N*sizeof(int), stream);

  count_kernel<<<(E+255)/256, 256, 0, stream>>>(ei, cnt, E);
  scan_partial<<<B1, 256, 0, stream>>>(cnt, bsum, N);
  scan_bsum<<<1, 64, 0, stream>>>(bsum, B1);
  scan_final<<<B1, 256, 0, stream>>>(cnt, bsum, off, cur, N, E);
  fill_kernel<<<(E+255)/256, 256, 0, stream>>>(ei, ea, cur, csr, E);

  pack_frag<<<48, 256, 0, stream>>>(Wih, WihF);
  pack_frag<<<48, 256, 0, stream>>>(Whh, WhhF);

  node_msg_kernel<<<1024, 256, 0, stream>>>(x, csr, off, mW1, mb1, mW2, mb2, agg, N);
  gru_mfma<<<512, 256, 0, stream>>>(agg, WihF, WhhF, bih, bhh, N);

  gstart_kernel<<<(G+256)/256, 256, 0, stream>>>(batch, gstart, N, G);
  pool_kernel<<<G, 64, 0, stream>>>(agg, gstart, pooled, G);
  readout_kernel<<<(G+255)/256, 256, 0, stream>>>(pooled, rW1, rb1, rW2, rb2, out, G);
}

// Round 5
// 504.524 us; speedup vs baseline: 12.8072x; 1.3191x over previous
//
#include <hip/hip_runtime.h>
#include <math.h>

#define CH 1024

typedef __attribute__((ext_vector_type(8))) short bf16x8;
typedef __attribute__((ext_vector_type(4))) float f32x4;

__device__ __forceinline__ float sigmoidf_(float x){ return 1.0f/(1.0f+__expf(-x)); }
__device__ __forceinline__ float tanhf_(float x){ return 1.0f - 2.0f/(1.0f+__expf(2.0f*x)); }
__device__ __forceinline__ unsigned short f2bf(float f){
  union{float f;unsigned u;}v; v.f=f;
  unsigned r = v.u + 0x7fffu + ((v.u>>16)&1u);
  return (unsigned short)(r>>16);
}
__device__ __forceinline__ float bf2f(unsigned short u){
  union{unsigned u; float f;} v; v.u = ((unsigned)u) << 16; return v.f;
}

// ---------- CSR build ----------
__global__ __launch_bounds__(256) void count_kernel(const int* __restrict__ ei, int* __restrict__ cnt, int E){
  int e = blockIdx.x*256 + threadIdx.x;
  if (e < E) atomicAdd(&cnt[ei[E + e]], 1);
}

__global__ __launch_bounds__(256) void scan_partial(const int* __restrict__ cnt, int* __restrict__ bsum, int N){
  __shared__ int s[256];
  int b = blockIdx.x, t = threadIdx.x;
  int base = b*CH;
  int sum = 0;
  for (int i = t; i < CH; i += 256){ int idx = base + i; sum += (idx < N) ? cnt[idx] : 0; }
  s[t] = sum; __syncthreads();
  for (int off = 128; off > 0; off >>= 1){ if (t < off) s[t] += s[t+off]; __syncthreads(); }
  if (t == 0) bsum[b] = s[0];
}

__global__ void scan_bsum(int* __restrict__ bsum, int B){
  if (threadIdx.x == 0 && blockIdx.x == 0){
    int acc = 0;
    for (int i = 0; i < B; i++){ int v = bsum[i]; bsum[i] = acc; acc += v; }
  }
}

__global__ __launch_bounds__(256) void scan_final(const int* __restrict__ cnt, const int* __restrict__ bsum,
                                                  int* __restrict__ off, int* __restrict__ cur,
                                                  float* __restrict__ degf, int N, int E){
  __shared__ int s[256];
  __shared__ int sx[256];
  int b = blockIdx.x, t = threadIdx.x;
  int i0 = b*CH + t*4;
  int v0 = (i0   < N) ? cnt[i0]   : 0;
  int v1 = (i0+1 < N) ? cnt[i0+1] : 0;
  int v2 = (i0+2 < N) ? cnt[i0+2] : 0;
  int v3 = (i0+3 < N) ? cnt[i0+3] : 0;
  s[t] = v0+v1+v2+v3; __syncthreads();
  if (t == 0){ int acc = bsum[b]; for (int i = 0; i < 256; i++){ sx[i] = acc; acc += s[i]; } }
  __syncthreads();
  int acc = sx[t];
  if (i0   < N){ off[i0]   = acc; cur[i0]   = acc; degf[i0]   = (float)v0; } acc += v0;
  if (i0+1 < N){ off[i0+1] = acc; cur[i0+1] = acc; degf[i0+1] = (float)v1; } acc += v1;
  if (i0+2 < N){ off[i0+2] = acc; cur[i0+2] = acc; degf[i0+2] = (float)v2; } acc += v2;
  if (i0+3 < N){ off[i0+3] = acc; cur[i0+3] = acc; degf[i0+3] = (float)v3; }
  if (b == 0 && t == 0) off[N] = E;
}

// fill packed CSR rows: csr2[p][0..11] = {x[src][0..8], ea[e][0..2]}  (48B, f4-aligned)
__global__ __launch_bounds__(256) void fill_kernel(const int* __restrict__ ei, const float* __restrict__ x,
                                                   const float* __restrict__ ea,
                                                   int* __restrict__ cur, float* __restrict__ csr2, int E){
  int e = blockIdx.x*256 + threadIdx.x;
  if (e < E){
    int src = ei[e];
    int p = atomicAdd(&cur[ei[E + e]], 1);
    const float* xr = x + (size_t)src*9;
    float4 f0 = make_float4(xr[0], xr[1], xr[2], xr[3]);
    float4 f1 = make_float4(xr[4], xr[5], xr[6], xr[7]);
    float4 f2 = make_float4(xr[8], ea[e*3], ea[e*3+1], ea[e*3+2]);
    float4* row = (float4*)(csr2 + (size_t)p*12);
    row[0] = f0; row[1] = f1; row[2] = f2;
  }
}

// pack a [192][64] gate matrix (natural [n][k]) into bf16 B-fragments:
// P[((c*2+kh)*64 + lane)*8 + j] = bf16(W[(c*16 + (lane&15))*64 + kh*32 + 8*(lane>>4) + j])
__global__ __launch_bounds__(256) void pack_frag(const float* __restrict__ W, unsigned short* __restrict__ P){
  int o = blockIdx.x*256 + threadIdx.x;
  if (o >= 12288) return;
  int j = o & 7, l = (o>>3)&63, kh = (o>>9)&1, c = o>>10;
  P[o] = f2bf(W[(c*16 + (l&15))*64 + kh*32 + 8*(l>>4) + j]);
}

// W1 [64][12] -> two B-fragment sets over K=32:
// B1: k0..11 = W1_hi, k16..27 = W1_hi (for the ml half);  B2: k0..11 = W1_lo, else 0.
__global__ __launch_bounds__(256) void pack_w1(const float* __restrict__ W1,
    unsigned short* __restrict__ B1, unsigned short* __restrict__ B2){
  int o = blockIdx.x*256 + threadIdx.x;
  if (o >= 2048) return;
  int j = o & 7, l = (o>>3) & 63, c = o >> 9;
  int n = c*16 + (l & 15);
  int kk = 8*(l>>4) + j;
  unsigned short b1v = 0, b2v = 0;
  if (kk < 12){
    float w = W1[n*12 + kk];
    unsigned short hi = f2bf(w);
    b1v = hi;
    b2v = f2bf(w - bf2f(hi));
  } else if (kk >= 16 && kk < 28){
    b1v = f2bf(W1[n*12 + (kk-16)]);
  }
  B1[o] = b1v; B2[o] = b2v;
}

// M = Wih @ W2 (192x64), dv = Wih @ b2 (192)
__global__ __launch_bounds__(256) void make_M(const float* __restrict__ Wih, const float* __restrict__ W2,
    const float* __restrict__ b2, float* __restrict__ M, float* __restrict__ dv){
  int idx = blockIdx.x*256 + threadIdx.x;
  if (idx >= 12288) return;
  int o = idx >> 6, k = idx & 63;
  float acc = 0.0f;
  for (int j = 0; j < 64; j++) acc += Wih[o*64+j]*W2[j*64+k];
  M[idx] = acc;
  if (k == 0){
    float a2 = 0.0f;
    for (int j = 0; j < 64; j++) a2 += Wih[o*64+j]*b2[j];
    dv[o] = a2;
  }
}

// ---------- per-node layer-1 + segment-sum on MFMA (16-edge tiles, hi/lo split) ----------
__global__ __launch_bounds__(256, 2) void node_msg_kernel(
    const float* __restrict__ csr2, const int* __restrict__ off,
    const unsigned short* __restrict__ W1B1v, const unsigned short* __restrict__ W1B2v,
    const float* __restrict__ b1, float* __restrict__ hsum, int N)
{
  int t = threadIdx.x, lane = t & 63;
  int s_ = lane & 15, g_ = lane >> 4;
  const bf16x8* B1 = (const bf16x8*)W1B1v;
  const bf16x8* B2 = (const bf16x8*)W1B2v;
  bf16x8 w1b1[4], w1b2[4];
  #pragma unroll
  for (int c = 0; c < 4; c++){ w1b1[c] = B1[c*64+lane]; w1b2[c] = B2[c*64+lane]; }
  float b1f[4], rb1[4];
  #pragma unroll
  for (int c = 0; c < 4; c++){ b1f[c] = b1[c*16+s_]; rb1[c] = fmaxf(b1f[c], 0.f); }
  bool hi_ = (g_ < 2);
  int wid = (blockIdx.x*256 + t) >> 6;
  int nw = gridDim.x*4;
  for (int node = wid; node < N; node += nw){
    int s = off[node], e = off[node+1];
    float accR[4] = {0.f,0.f,0.f,0.f};
    int ntiles = (e - s + 15) >> 4;
    for (int tt = 0; tt < ntiles; tt++){
      int p = s + tt*16 + s_;
      float4 va = make_float4(0,0,0,0), vb = make_float4(0,0,0,0);
      if (p < e){
        const float4* row = (const float4*)(csr2 + (size_t)p*12);
        if ((g_ & 1) == 0){ va = row[0]; vb = row[1]; }
        else { va = row[2]; }
      }
      float mv[8] = {va.x,va.y,va.z,va.w,vb.x,vb.y,vb.z,vb.w};
      bf16x8 af, ah;
      #pragma unroll
      for (int i = 0; i < 8; i++){
        unsigned short mh = f2bf(mv[i]);
        unsigned short v;
        if (hi_) v = mh;
        else v = f2bf(mv[i] - bf2f(mh));
        af[i] = (short)v;
        ah[i] = hi_ ? (short)v : (short)0;
      }
      #pragma unroll
      for (int c = 0; c < 4; c++){
        f32x4 acc; acc[0]=b1f[c]; acc[1]=b1f[c]; acc[2]=b1f[c]; acc[3]=b1f[c];
        acc = __builtin_amdgcn_mfma_f32_16x16x32_bf16(af, w1b1[c], acc, 0,0,0);
        acc = __builtin_amdgcn_mfma_f32_16x16x32_bf16(ah, w1b2[c], acc, 0,0,0);
        accR[c] += fmaxf(acc[0],0.f)+fmaxf(acc[1],0.f)+fmaxf(acc[2],0.f)+fmaxf(acc[3],0.f);
      }
    }
    float npad = (float)(ntiles*16 - (e - s));
    #pragma unroll
    for (int c = 0; c < 4; c++){
      float v = accR[c] - npad*rb1[c];
      v += __shfl_xor(v, 16, 64);
      v += __shfl_xor(v, 32, 64);
      accR[c] = v;
    }
    float outv = (g_==0) ? accR[0] : ((g_==1) ? accR[1] : ((g_==2) ? accR[2] : accR[3]));
    hsum[(size_t)node*64 + lane] = outv;
  }
}

// ---------- fused (M@hsum + deg*dv + bih) + 6-step GRU on matrix cores ----------
__global__ __launch_bounds__(256, 2) void gru_mfma(
    float* hsumh,   // in: hsum [N][64]; out: h [N][64] (same buffer, per-tile in-place)
    const unsigned short* __restrict__ MF, const unsigned short* __restrict__ WhhF,
    const float* __restrict__ bih, const float* __restrict__ bhh,
    const float* __restrict__ dv, const float* __restrict__ degf, int N)
{
  __shared__ unsigned short hbuf[4][1024];
  int t = threadIdx.x, lane = t & 63, w = t >> 6;
  int s_ = lane & 15, g_ = lane >> 4;
  unsigned short* hb = hbuf[w];

  const bf16x8* WhhV = (const bf16x8*)WhhF;
  const bf16x8* MFV  = (const bf16x8*)MF;
  bf16x8 whhf[24];
  #pragma unroll
  for (int i = 0; i < 24; i++) whhf[i] = WhhV[i*64 + lane];
  float bi[12], bh[12], dvf[12];
  #pragma unroll
  for (int c = 0; c < 12; c++){ bi[c] = bih[c*16 + s_]; bh[c] = bhh[c*16 + s_]; dvf[c] = dv[c*16 + s_]; }

  int wid = (blockIdx.x*256 + t) >> 6;
  int nw = gridDim.x*4;
  int NT = (N + 15) >> 4;
  for (int tile = wid; tile < NT; tile += nw){
    // ---- A-fragments of hsum tile (16 nodes x 64 feats) ----
    int nodeA = tile*16 + s_; if (nodeA > N-1) nodeA = N-1;
    const float* ab = hsumh + (size_t)nodeA*64 + g_*8;
    float4 v0 = *(const float4*)(ab);
    float4 v1 = *(const float4*)(ab+4);
    float4 v2 = *(const float4*)(ab+32);
    float4 v3 = *(const float4*)(ab+36);
    bf16x8 a0, a1;
    a0[0]=(short)f2bf(v0.x); a0[1]=(short)f2bf(v0.y); a0[2]=(short)f2bf(v0.z); a0[3]=(short)f2bf(v0.w);
    a0[4]=(short)f2bf(v1.x); a0[5]=(short)f2bf(v1.y); a0[6]=(short)f2bf(v1.z); a0[7]=(short)f2bf(v1.w);
    a1[0]=(short)f2bf(v2.x); a1[1]=(short)f2bf(v2.y); a1[2]=(short)f2bf(v2.z); a1[3]=(short)f2bf(v2.w);
    a1[4]=(short)f2bf(v3.x); a1[5]=(short)f2bf(v3.y); a1[6]=(short)f2bf(v3.z); a1[7]=(short)f2bf(v3.w);

    // ---- gi = M@hsum + deg*dv + bih, kept in registers ----
    float4 dr = *(const float4*)(degf + tile*16 + 4*g_);
    float drr[4] = {dr.x, dr.y, dr.z, dr.w};
    f32x4 gia[12];
    #pragma unroll
    for (int c = 0; c < 12; c++){
      f32x4 acc;
      #pragma unroll
      for (int r = 0; r < 4; r++) acc[r] = bi[c] + drr[r]*dvf[c];
      acc = __builtin_amdgcn_mfma_f32_16x16x32_bf16(a0, MFV[(c*2+0)*64 + lane], acc, 0, 0, 0);
      acc = __builtin_amdgcn_mfma_f32_16x16x32_bf16(a1, MFV[(c*2+1)*64 + lane], acc, 0, 0, 0);
      gia[c] = acc;
    }

    // ---- 6 GRU steps ----
    f32x4 hD[4];
    #pragma unroll
    for (int c = 0; c < 4; c++){ hD[c][0]=0.f; hD[c][1]=0.f; hD[c][2]=0.f; hD[c][3]=0.f; }
    bf16x8 h0 = {0,0,0,0,0,0,0,0};
    bf16x8 h1 = {0,0,0,0,0,0,0,0};
    for (int st = 0; st < 6; st++){
      #pragma unroll
      for (int c = 0; c < 4; c++){
        f32x4 aR, aZ, aN;
        aR[0]=bh[c];   aR[1]=bh[c];   aR[2]=bh[c];   aR[3]=bh[c];
        aZ[0]=bh[4+c]; aZ[1]=bh[4+c]; aZ[2]=bh[4+c]; aZ[3]=bh[4+c];
        aN[0]=bh[8+c]; aN[1]=bh[8+c]; aN[2]=bh[8+c]; aN[3]=bh[8+c];
        aR = __builtin_amdgcn_mfma_f32_16x16x32_bf16(h0, whhf[c*2],       aR, 0,0,0);
        aR = __builtin_amdgcn_mfma_f32_16x16x32_bf16(h1, whhf[c*2+1],     aR, 0,0,0);
        aZ = __builtin_amdgcn_mfma_f32_16x16x32_bf16(h0, whhf[(4+c)*2],   aZ, 0,0,0);
        aZ = __builtin_amdgcn_mfma_f32_16x16x32_bf16(h1, whhf[(4+c)*2+1], aZ, 0,0,0);
        aN = __builtin_amdgcn_mfma_f32_16x16x32_bf16(h0, whhf[(8+c)*2],   aN, 0,0,0);
        aN = __builtin_amdgcn_mfma_f32_16x16x32_bf16(h1, whhf[(8+c)*2+1], aN, 0,0,0);
        #pragma unroll
        for (int r = 0; r < 4; r++){
          float rr = sigmoidf_(gia[c][r]   + aR[r]);
          float zz = sigmoidf_(gia[4+c][r] + aZ[r]);
          float nn = tanhf_(gia[8+c][r] + rr*aN[r]);
          hD[c][r] = (1.0f - zz)*nn + zz*hD[c][r];
        }
      }
      if (st < 5){
        #pragma unroll
        for (int c = 0; c < 4; c++){
          #pragma unroll
          for (int r = 0; r < 4; r++){
            int nl = 4*g_ + r;
            int idx = (nl*64 + 16*c + s_) ^ ((nl & 7) << 3);
            hb[idx] = f2bf(hD[c][r]);
          }
        }
        int r0 = (s_*64 +      8*g_) ^ ((s_ & 7) << 3);
        int r1 = (s_*64 + 32 + 8*g_) ^ ((s_ & 7) << 3);
        h0 = *(const bf16x8*)(hb + r0);
        h1 = *(const bf16x8*)(hb + r1);
      }
    }
    // ---- store h (overwrites this tile's hsum rows; tiles are disjoint) ----
    #pragma unroll
    for (int c = 0; c < 4; c++){
      #pragma unroll
      for (int r = 0; r < 4; r++){
        int node = tile*16 + 4*g_ + r;
        if (node < N) hsumh[(size_t)node*64 + 16*c + s_] = hD[c][r];
      }
    }
  }
}

// ---------- graph ranges via binary search on sorted batch ----------
__global__ __launch_bounds__(256) void gstart_kernel(const int* __restrict__ batch, int* __restrict__ gstart, int N, int G){
  int g = blockIdx.x*256 + threadIdx.x;
  if (g > G) return;
  int lo = 0, hi = N;
  while (lo < hi){ int mid = (lo + hi) >> 1; if (batch[mid] < g) lo = mid + 1; else hi = mid; }
  gstart[g] = lo;
}

// wave per graph: mean over the graph's node range
__global__ __launch_bounds__(64) void pool_kernel(const float* __restrict__ hout, const int* __restrict__ gstart,
                                                  float* __restrict__ pooled, int G){
  int g = blockIdx.x; int lane = threadIdx.x;
  int s = gstart[g], e = gstart[g+1];
  float acc = 0.0f;
  for (int n = s; n < e; n++) acc += hout[(size_t)n*64 + lane];
  float c = fmaxf((float)(e - s), 1.0f);
  pooled[g*64 + lane] = acc / c;
}

// thread per graph: out = W2 relu(W1 pooled + b1) + b2
__global__ __launch_bounds__(256) void readout_kernel(
  const float* __restrict__ pooled,
  const float* __restrict__ W1, const float* __restrict__ b1,
  const float* __restrict__ W2, const float* __restrict__ b2,
  float* __restrict__ out, int G)
{
  __shared__ __align__(16) float sW1[64*64];
  __shared__ float sb1[64], sW2v[64];
  for (int i = threadIdx.x; i < 64*64; i += 256) sW1[i] = W1[i];
  if (threadIdx.x < 64){ sb1[threadIdx.x] = b1[threadIdx.x]; sW2v[threadIdx.x] = W2[threadIdx.x]; }
  __syncthreads();
  int g = blockIdx.x*256 + threadIdx.x;
  if (g >= G) return;
  float p[64];
  const float4* pp = (const float4*)(pooled + g*64);
  #pragma unroll
  for (int k4 = 0; k4 < 16; k4++){
    float4 v = pp[k4];
    p[4*k4] = v.x; p[4*k4+1] = v.y; p[4*k4+2] = v.z; p[4*k4+3] = v.w;
  }
  float acc = b2[0];
  for (int j = 0; j < 64; j++){
    const float4* wv4 = (const float4*)(sW1 + j*64);
    float tacc = sb1[j];
    #pragma unroll
    for (int k4 = 0; k4 < 16; k4++){
      float4 wv = wv4[k4];
      tacc += wv.x*p[4*k4] + wv.y*p[4*k4+1] + wv.z*p[4*k4+2] + wv.w*p[4*k4+3];
    }
    acc += sW2v[j]*fmaxf(tacc, 0.0f);
  }
  out[g] = acc;
}

extern "C" void kernel_launch(void* const* d_in, const int* in_sizes, int n_in,
                              void* d_out, int out_size, void* d_ws, size_t ws_size,
                              hipStream_t stream)
{
  const float* x    = (const float*)d_in[0];
  const int*   ei   = (const int*)  d_in[1];
  const float* ea   = (const float*)d_in[2];
  const int*   batch= (const int*)  d_in[3];
  const float* mW1  = (const float*)d_in[4];
  const float* mb1  = (const float*)d_in[5];
  const float* mW2  = (const float*)d_in[6];
  const float* mb2  = (const float*)d_in[7];
  const float* Wih  = (const float*)d_in[8];
  const float* Whh  = (const float*)d_in[9];
  const float* bih  = (const float*)d_in[10];
  const float* bhh  = (const float*)d_in[11];
  const float* rW1  = (const float*)d_in[12];
  const float* rb1  = (const float*)d_in[13];
  const float* rW2  = (const float*)d_in[14];
  const float* rb2  = (const float*)d_in[15];
  float* out = (float*)d_out;

  int N = in_sizes[0] / 9;
  int E = in_sizes[1] / 2;
  int G = out_size;

  float* fws    = (float*)d_ws;
  float* hsum   = fws;                          // 64N floats (in: hsum, out: h)
  float* csr2   = hsum + (size_t)64*N;          // 12E floats
  float* degf   = csr2 + (size_t)12*E;          // N+16
  float* M      = degf + (size_t)(N+16);        // 12288
  float* dv     = M + 12288;                    // 192
  float* pooled = dv + 192;                     // 64G
  unsigned short* MF   = (unsigned short*)(pooled + (size_t)64*G);  // 12288
  unsigned short* WhhF = MF + 12288;                                 // 12288
  unsigned short* W1B1 = WhhF + 12288;                               // 2048
  unsigned short* W1B2 = W1B1 + 2048;                                // 2048
  int*   iws    = (int*)(W1B2 + 2048);
  int*   cnt    = iws;                          // N
  int*   off    = cnt + N;                      // N+1
  int*   cur    = off + N + 1;                  // N
  int*   bsum   = cur + N;                      // up to 1024
  int*   gstart = bsum + 1024;                  // G+1

  int B1 = (N + CH - 1) / CH;

  hipMemsetAsync(cnt, 0, (size_t)N*sizeof(int), stream);
  hipMemsetAsync(degf + N, 0, 16*sizeof(float), stream);

  count_kernel<<<(E+255)/256, 256, 0, stream>>>(ei, cnt, E);
  scan_partial<<<B1, 256, 0, stream>>>(cnt, bsum, N);
  scan_bsum<<<1, 64, 0, stream>>>(bsum, B1);
  scan_final<<<B1, 256, 0, stream>>>(cnt, bsum, off, cur, degf, N, E);
  fill_kernel<<<(E+255)/256, 256, 0, stream>>>(ei, x, ea, cur, csr2, E);

  pack_w1<<<8, 256, 0, stream>>>(mW1, W1B1, W1B2);
  make_M<<<48, 256, 0, stream>>>(Wih, mW2, mb2, M, dv);
  pack_frag<<<48, 256, 0, stream>>>(M, MF);
  pack_frag<<<48, 256, 0, stream>>>(Whh, WhhF);

  node_msg_kernel<<<1024, 256, 0, stream>>>(csr2, off, W1B1, W1B2, mb1, hsum, N);
  gru_mfma<<<512, 256, 0, stream>>>(hsum, MF, WhhF, bih, bhh, dv, degf, N);

  gstart_kernel<<<(G+256)/256, 256, 0, stream>>>(batch, gstart, N, G);
  pool_kernel<<<G, 64, 0, stream>>>(hsum, gstart, pooled, G);
  readout_kernel<<<(G+255)/256, 256, 0, stream>>>(pooled, rW1, rb1, rW2, rb2, out, G);
}

// Round 6
// 409.773 us; speedup vs baseline: 15.7685x; 1.2312x over previous
//
#include <hip/hip_runtime.h>
#include <math.h>

#define CH 1024

typedef __attribute__((ext_vector_type(8))) short bf16x8;
typedef __attribute__((ext_vector_type(4))) float f32x4;

__device__ __forceinline__ float sigmoidf_(float x){ return 1.0f/(1.0f+__expf(-x)); }
__device__ __forceinline__ float tanhf_(float x){ return 1.0f - 2.0f/(1.0f+__expf(2.0f*x)); }
__device__ __forceinline__ unsigned short f2bf(float f){
  union{float f;unsigned u;}v; v.f=f;
  unsigned r = v.u + 0x7fffu + ((v.u>>16)&1u);
  return (unsigned short)(r>>16);
}
__device__ __forceinline__ float bf2f(unsigned short u){
  union{unsigned u; float f;} v; v.u = ((unsigned)u) << 16; return v.f;
}

// ---------- CSR build ----------
__global__ __launch_bounds__(256) void count_kernel(const int* __restrict__ ei, int* __restrict__ cnt, int E){
  int e = blockIdx.x*256 + threadIdx.x;
  if (e < E) atomicAdd(&cnt[ei[E + e]], 1);
}

__global__ __launch_bounds__(256) void scan_partial(const int* __restrict__ cnt, int* __restrict__ bsum, int N){
  __shared__ int s[256];
  int b = blockIdx.x, t = threadIdx.x;
  int base = b*CH;
  int sum = 0;
  for (int i = t; i < CH; i += 256){ int idx = base + i; sum += (idx < N) ? cnt[idx] : 0; }
  s[t] = sum; __syncthreads();
  for (int off = 128; off > 0; off >>= 1){ if (t < off) s[t] += s[t+off]; __syncthreads(); }
  if (t == 0) bsum[b] = s[0];
}

__global__ void scan_bsum(int* __restrict__ bsum, int B){
  if (threadIdx.x == 0 && blockIdx.x == 0){
    int acc = 0;
    for (int i = 0; i < B; i++){ int v = bsum[i]; bsum[i] = acc; acc += v; }
  }
}

__global__ __launch_bounds__(256) void scan_final(const int* __restrict__ cnt, const int* __restrict__ bsum,
                                                  int* __restrict__ off, int* __restrict__ cur,
                                                  float* __restrict__ degf, int N, int E){
  __shared__ int s[256];
  __shared__ int sx[256];
  int b = blockIdx.x, t = threadIdx.x;
  int i0 = b*CH + t*4;
  int v0 = (i0   < N) ? cnt[i0]   : 0;
  int v1 = (i0+1 < N) ? cnt[i0+1] : 0;
  int v2 = (i0+2 < N) ? cnt[i0+2] : 0;
  int v3 = (i0+3 < N) ? cnt[i0+3] : 0;
  s[t] = v0+v1+v2+v3; __syncthreads();
  if (t == 0){ int acc = bsum[b]; for (int i = 0; i < 256; i++){ sx[i] = acc; acc += s[i]; } }
  __syncthreads();
  int acc = sx[t];
  if (i0   < N){ off[i0]   = acc; cur[i0]   = acc; degf[i0]   = (float)v0; } acc += v0;
  if (i0+1 < N){ off[i0+1] = acc; cur[i0+1] = acc; degf[i0+1] = (float)v1; } acc += v1;
  if (i0+2 < N){ off[i0+2] = acc; cur[i0+2] = acc; degf[i0+2] = (float)v2; } acc += v2;
  if (i0+3 < N){ off[i0+3] = acc; cur[i0+3] = acc; degf[i0+3] = (float)v3; }
  if (b == 0 && t == 0) off[N] = E;
}

// fill packed CSR rows: csr2[p][0..11] = {x[src][0..8], ea[e][0..2]}  (48B, f4-aligned)
__global__ __launch_bounds__(256) void fill_kernel(const int* __restrict__ ei, const float* __restrict__ x,
                                                   const float* __restrict__ ea,
                                                   int* __restrict__ cur, float* __restrict__ csr2, int E){
  int e = blockIdx.x*256 + threadIdx.x;
  if (e < E){
    int src = ei[e];
    int p = atomicAdd(&cur[ei[E + e]], 1);
    const float* xr = x + (size_t)src*9;
    float4 f0 = make_float4(xr[0], xr[1], xr[2], xr[3]);
    float4 f1 = make_float4(xr[4], xr[5], xr[6], xr[7]);
    float4 f2 = make_float4(xr[8], ea[e*3], ea[e*3+1], ea[e*3+2]);
    float4* row = (float4*)(csr2 + (size_t)p*12);
    row[0] = f0; row[1] = f1; row[2] = f2;
  }
}

// pack a [192][64] gate matrix (natural [n][k]) into bf16 B-fragments:
// P[((c*2+kh)*64 + lane)*8 + j] = bf16(W[(c*16 + (lane&15))*64 + kh*32 + 8*(lane>>4) + j])
__global__ __launch_bounds__(256) void pack_frag(const float* __restrict__ W, unsigned short* __restrict__ P){
  int o = blockIdx.x*256 + threadIdx.x;
  if (o >= 12288) return;
  int j = o & 7, l = (o>>3)&63, kh = (o>>9)&1, c = o>>10;
  P[o] = f2bf(W[(c*16 + (l&15))*64 + kh*32 + 8*(l>>4) + j]);
}

// W1 [64][12] -> two B-fragment sets over K=32:
// B1: k0..11 = W1_hi, k16..27 = W1_hi (for the ml half);  B2: k0..11 = W1_lo, else 0.
__global__ __launch_bounds__(256) void pack_w1(const float* __restrict__ W1,
    unsigned short* __restrict__ B1, unsigned short* __restrict__ B2){
  int o = blockIdx.x*256 + threadIdx.x;
  if (o >= 2048) return;
  int j = o & 7, l = (o>>3) & 63, c = o >> 9;
  int n = c*16 + (l & 15);
  int kk = 8*(l>>4) + j;
  unsigned short b1v = 0, b2v = 0;
  if (kk < 12){
    float w = W1[n*12 + kk];
    unsigned short hi = f2bf(w);
    b1v = hi;
    b2v = f2bf(w - bf2f(hi));
  } else if (kk >= 16 && kk < 28){
    b1v = f2bf(W1[n*12 + (kk-16)]);
  }
  B1[o] = b1v; B2[o] = b2v;
}

// M = Wih @ W2 (192x64), dv = Wih @ b2 (192)
__global__ __launch_bounds__(256) void make_M(const float* __restrict__ Wih, const float* __restrict__ W2,
    const float* __restrict__ b2, float* __restrict__ M, float* __restrict__ dv){
  int idx = blockIdx.x*256 + threadIdx.x;
  if (idx >= 12288) return;
  int o = idx >> 6, k = idx & 63;
  float acc = 0.0f;
  for (int j = 0; j < 64; j++) acc += Wih[o*64+j]*W2[j*64+k];
  M[idx] = acc;
  if (k == 0){
    float a2 = 0.0f;
    for (int j = 0; j < 64; j++) a2 += Wih[o*64+j]*b2[j];
    dv[o] = a2;
  }
}

// ---------- per-node layer-1 + segment-sum on MFMA (16-edge tiles, hi/lo split) ----------
__global__ __launch_bounds__(256, 2) void node_msg_kernel(
    const float* __restrict__ csr2, const int* __restrict__ off,
    const unsigned short* __restrict__ W1B1v, const unsigned short* __restrict__ W1B2v,
    const float* __restrict__ b1, float* __restrict__ hsum, int N)
{
  int t = threadIdx.x, lane = t & 63;
  int s_ = lane & 15, g_ = lane >> 4;
  const bf16x8* B1 = (const bf16x8*)W1B1v;
  const bf16x8* B2 = (const bf16x8*)W1B2v;
  bf16x8 w1b1[4], w1b2[4];
  #pragma unroll
  for (int c = 0; c < 4; c++){ w1b1[c] = B1[c*64+lane]; w1b2[c] = B2[c*64+lane]; }
  float b1f[4], rb1[4];
  #pragma unroll
  for (int c = 0; c < 4; c++){ b1f[c] = b1[c*16+s_]; rb1[c] = fmaxf(b1f[c], 0.f); }
  bool hi_ = (g_ < 2);
  int wid = (blockIdx.x*256 + t) >> 6;
  int nw = gridDim.x*4;
  for (int node = wid; node < N; node += nw){
    int s = off[node], e = off[node+1];
    float accR[4] = {0.f,0.f,0.f,0.f};
    int ntiles = (e - s + 15) >> 4;
    for (int tt = 0; tt < ntiles; tt++){
      int p = s + tt*16 + s_;
      float4 va = make_float4(0,0,0,0), vb = make_float4(0,0,0,0);
      if (p < e){
        const float4* row = (const float4*)(csr2 + (size_t)p*12);
        if ((g_ & 1) == 0){ va = row[0]; vb = row[1]; }
        else { va = row[2]; }
      }
      float mv[8] = {va.x,va.y,va.z,va.w,vb.x,vb.y,vb.z,vb.w};
      bf16x8 af, ah;
      #pragma unroll
      for (int i = 0; i < 8; i++){
        unsigned short mh = f2bf(mv[i]);
        unsigned short v;
        if (hi_) v = mh;
        else v = f2bf(mv[i] - bf2f(mh));
        af[i] = (short)v;
        ah[i] = hi_ ? (short)v : (short)0;
      }
      #pragma unroll
      for (int c = 0; c < 4; c++){
        f32x4 acc; acc[0]=b1f[c]; acc[1]=b1f[c]; acc[2]=b1f[c]; acc[3]=b1f[c];
        acc = __builtin_amdgcn_mfma_f32_16x16x32_bf16(af, w1b1[c], acc, 0,0,0);
        acc = __builtin_amdgcn_mfma_f32_16x16x32_bf16(ah, w1b2[c], acc, 0,0,0);
        accR[c] += fmaxf(acc[0],0.f)+fmaxf(acc[1],0.f)+fmaxf(acc[2],0.f)+fmaxf(acc[3],0.f);
      }
    }
    float npad = (float)(ntiles*16 - (e - s));
    #pragma unroll
    for (int c = 0; c < 4; c++){
      float v = accR[c] - npad*rb1[c];
      v += __shfl_xor(v, 16, 64);
      v += __shfl_xor(v, 32, 64);
      accR[c] = v;
    }
    float outv = (g_==0) ? accR[0] : ((g_==1) ? accR[1] : ((g_==2) ? accR[2] : accR[3]));
    hsum[(size_t)node*64 + lane] = outv;
  }
}

// ---------- fused (M@hsum + deg*dv + bih) + 6-step GRU on matrix cores ----------
// __launch_bounds__(256,1): per-lane state (whhf 96 + gia 48 + hD 16 + frags/scalars ~60)
// needs ~230 VGPRs; the (256,2) cap of 128 forced ~80 regs of scratch spill = ~350 MB/dispatch
// of HBM spill traffic (R5 counters: FETCH 193 MB, WRITE 178 MB vs 26+26 algorithmic).
__global__ __launch_bounds__(256, 1) void gru_mfma(
    float* hsumh,   // in: hsum [N][64]; out: h [N][64] (same buffer, per-tile in-place)
    const unsigned short* __restrict__ MF, const unsigned short* __restrict__ WhhF,
    const float* __restrict__ bih, const float* __restrict__ bhh,
    const float* __restrict__ dv, const float* __restrict__ degf, int N)
{
  __shared__ unsigned short hbuf[4][1024];
  int t = threadIdx.x, lane = t & 63, w = t >> 6;
  int s_ = lane & 15, g_ = lane >> 4;
  unsigned short* hb = hbuf[w];

  const bf16x8* WhhV = (const bf16x8*)WhhF;
  const bf16x8* MFV  = (const bf16x8*)MF;
  bf16x8 whhf[24];
  #pragma unroll
  for (int i = 0; i < 24; i++) whhf[i] = WhhV[i*64 + lane];
  float bi[12], bh[12], dvf[12];
  #pragma unroll
  for (int c = 0; c < 12; c++){ bi[c] = bih[c*16 + s_]; bh[c] = bhh[c*16 + s_]; dvf[c] = dv[c*16 + s_]; }

  int wid = (blockIdx.x*256 + t) >> 6;
  int nw = gridDim.x*4;
  int NT = (N + 15) >> 4;
  for (int tile = wid; tile < NT; tile += nw){
    // ---- A-fragments of hsum tile (16 nodes x 64 feats) ----
    int nodeA = tile*16 + s_; if (nodeA > N-1) nodeA = N-1;
    const float* ab = hsumh + (size_t)nodeA*64 + g_*8;
    float4 v0 = *(const float4*)(ab);
    float4 v1 = *(const float4*)(ab+4);
    float4 v2 = *(const float4*)(ab+32);
    float4 v3 = *(const float4*)(ab+36);
    bf16x8 a0, a1;
    a0[0]=(short)f2bf(v0.x); a0[1]=(short)f2bf(v0.y); a0[2]=(short)f2bf(v0.z); a0[3]=(short)f2bf(v0.w);
    a0[4]=(short)f2bf(v1.x); a0[5]=(short)f2bf(v1.y); a0[6]=(short)f2bf(v1.z); a0[7]=(short)f2bf(v1.w);
    a1[0]=(short)f2bf(v2.x); a1[1]=(short)f2bf(v2.y); a1[2]=(short)f2bf(v2.z); a1[3]=(short)f2bf(v2.w);
    a1[4]=(short)f2bf(v3.x); a1[5]=(short)f2bf(v3.y); a1[6]=(short)f2bf(v3.z); a1[7]=(short)f2bf(v3.w);

    // ---- gi = M@hsum + deg*dv + bih, kept in registers ----
    float4 dr = *(const float4*)(degf + tile*16 + 4*g_);
    float drr[4] = {dr.x, dr.y, dr.z, dr.w};
    f32x4 gia[12];
    #pragma unroll
    for (int c = 0; c < 12; c++){
      f32x4 acc;
      #pragma unroll
      for (int r = 0; r < 4; r++) acc[r] = bi[c] + drr[r]*dvf[c];
      acc = __builtin_amdgcn_mfma_f32_16x16x32_bf16(a0, MFV[(c*2+0)*64 + lane], acc, 0, 0, 0);
      acc = __builtin_amdgcn_mfma_f32_16x16x32_bf16(a1, MFV[(c*2+1)*64 + lane], acc, 0, 0, 0);
      gia[c] = acc;
    }

    // ---- 6 GRU steps ----
    f32x4 hD[4];
    #pragma unroll
    for (int c = 0; c < 4; c++){ hD[c][0]=0.f; hD[c][1]=0.f; hD[c][2]=0.f; hD[c][3]=0.f; }
    bf16x8 h0 = {0,0,0,0,0,0,0,0};
    bf16x8 h1 = {0,0,0,0,0,0,0,0};
    for (int st = 0; st < 6; st++){
      #pragma unroll
      for (int c = 0; c < 4; c++){
        f32x4 aR, aZ, aN;
        aR[0]=bh[c];   aR[1]=bh[c];   aR[2]=bh[c];   aR[3]=bh[c];
        aZ[0]=bh[4+c]; aZ[1]=bh[4+c]; aZ[2]=bh[4+c]; aZ[3]=bh[4+c];
        aN[0]=bh[8+c]; aN[1]=bh[8+c]; aN[2]=bh[8+c]; aN[3]=bh[8+c];
        aR = __builtin_amdgcn_mfma_f32_16x16x32_bf16(h0, whhf[c*2],       aR, 0,0,0);
        aR = __builtin_amdgcn_mfma_f32_16x16x32_bf16(h1, whhf[c*2+1],     aR, 0,0,0);
        aZ = __builtin_amdgcn_mfma_f32_16x16x32_bf16(h0, whhf[(4+c)*2],   aZ, 0,0,0);
        aZ = __builtin_amdgcn_mfma_f32_16x16x32_bf16(h1, whhf[(4+c)*2+1], aZ, 0,0,0);
        aN = __builtin_amdgcn_mfma_f32_16x16x32_bf16(h0, whhf[(8+c)*2],   aN, 0,0,0);
        aN = __builtin_amdgcn_mfma_f32_16x16x32_bf16(h1, whhf[(8+c)*2+1], aN, 0,0,0);
        #pragma unroll
        for (int r = 0; r < 4; r++){
          float rr = sigmoidf_(gia[c][r]   + aR[r]);
          float zz = sigmoidf_(gia[4+c][r] + aZ[r]);
          float nn = tanhf_(gia[8+c][r] + rr*aN[r]);
          hD[c][r] = (1.0f - zz)*nn + zz*hD[c][r];
        }
      }
      if (st < 5){
        #pragma unroll
        for (int c = 0; c < 4; c++){
          #pragma unroll
          for (int r = 0; r < 4; r++){
            int nl = 4*g_ + r;
            int idx = (nl*64 + 16*c + s_) ^ ((nl & 7) << 3);
            hb[idx] = f2bf(hD[c][r]);
          }
        }
        int r0 = (s_*64 +      8*g_) ^ ((s_ & 7) << 3);
        int r1 = (s_*64 + 32 + 8*g_) ^ ((s_ & 7) << 3);
        h0 = *(const bf16x8*)(hb + r0);
        h1 = *(const bf16x8*)(hb + r1);
      }
    }
    // ---- store h (overwrites this tile's hsum rows; tiles are disjoint) ----
    #pragma unroll
    for (int c = 0; c < 4; c++){
      #pragma unroll
      for (int r = 0; r < 4; r++){
        int node = tile*16 + 4*g_ + r;
        if (node < N) hsumh[(size_t)node*64 + 16*c + s_] = hD[c][r];
      }
    }
  }
}

// ---------- graph ranges via binary search on sorted batch ----------
__global__ __launch_bounds__(256) void gstart_kernel(const int* __restrict__ batch, int* __restrict__ gstart, int N, int G){
  int g = blockIdx.x*256 + threadIdx.x;
  if (g > G) return;
  int lo = 0, hi = N;
  while (lo < hi){ int mid = (lo + hi) >> 1; if (batch[mid] < g) lo = mid + 1; else hi = mid; }
  gstart[g] = lo;
}

// wave per graph: mean over the graph's node range
__global__ __launch_bounds__(64) void pool_kernel(const float* __restrict__ hout, const int* __restrict__ gstart,
                                                  float* __restrict__ pooled, int G){
  int g = blockIdx.x; int lane = threadIdx.x;
  int s = gstart[g], e = gstart[g+1];
  float acc = 0.0f;
  for (int n = s; n < e; n++) acc += hout[(size_t)n*64 + lane];
  float c = fmaxf((float)(e - s), 1.0f);
  pooled[g*64 + lane] = acc / c;
}

// thread per graph: out = W2 relu(W1 pooled + b1) + b2
__global__ __launch_bounds__(256) void readout_kernel(
  const float* __restrict__ pooled,
  const float* __restrict__ W1, const float* __restrict__ b1,
  const float* __restrict__ W2, const float* __restrict__ b2,
  float* __restrict__ out, int G)
{
  __shared__ __align__(16) float sW1[64*64];
  __shared__ float sb1[64], sW2v[64];
  for (int i = threadIdx.x; i < 64*64; i += 256) sW1[i] = W1[i];
  if (threadIdx.x < 64){ sb1[threadIdx.x] = b1[threadIdx.x]; sW2v[threadIdx.x] = W2[threadIdx.x]; }
  __syncthreads();
  int g = blockIdx.x*256 + threadIdx.x;
  if (g >= G) return;
  float p[64];
  const float4* pp = (const float4*)(pooled + g*64);
  #pragma unroll
  for (int k4 = 0; k4 < 16; k4++){
    float4 v = pp[k4];
    p[4*k4] = v.x; p[4*k4+1] = v.y; p[4*k4+2] = v.z; p[4*k4+3] = v.w;
  }
  float acc = b2[0];
  for (int j = 0; j < 64; j++){
    const float4* wv4 = (const float4*)(sW1 + j*64);
    float tacc = sb1[j];
    #pragma unroll
    for (int k4 = 0; k4 < 16; k4++){
      float4 wv = wv4[k4];
      tacc += wv.x*p[4*k4] + wv.y*p[4*k4+1] + wv.z*p[4*k4+2] + wv.w*p[4*k4+3];
    }
    acc += sW2v[j]*fmaxf(tacc, 0.0f);
  }
  out[g] = acc;
}

extern "C" void kernel_launch(void* const* d_in, const int* in_sizes, int n_in,
                              void* d_out, int out_size, void* d_ws, size_t ws_size,
                              hipStream_t stream)
{
  const float* x    = (const float*)d_in[0];
  const int*   ei   = (const int*)  d_in[1];
  const float* ea   = (const float*)d_in[2];
  const int*   batch= (const int*)  d_in[3];
  const float* mW1  = (const float*)d_in[4];
  const float* mb1  = (const float*)d_in[5];
  const float* mW2  = (const float*)d_in[6];
  const float* mb2  = (const float*)d_in[7];
  const float* Wih  = (const float*)d_in[8];
  const float* Whh  = (const float*)d_in[9];
  const float* bih  = (const float*)d_in[10];
  const float* bhh  = (const float*)d_in[11];
  const float* rW1  = (const float*)d_in[12];
  const float* rb1  = (const float*)d_in[13];
  const float* rW2  = (const float*)d_in[14];
  const float* rb2  = (const float*)d_in[15];
  float* out = (float*)d_out;

  int N = in_sizes[0] / 9;
  int E = in_sizes[1] / 2;
  int G = out_size;

  float* fws    = (float*)d_ws;
  float* hsum   = fws;                          // 64N floats (in: hsum, out: h)
  float* csr2   = hsum + (size_t)64*N;          // 12E floats
  float* degf   = csr2 + (size_t)12*E;          // N+16
  float* M      = degf + (size_t)(N+16);        // 12288
  float* dv     = M + 12288;                    // 192
  float* pooled = dv + 192;                     // 64G
  unsigned short* MF   = (unsigned short*)(pooled + (size_t)64*G);  // 12288
  unsigned short* WhhF = MF + 12288;                                 // 12288
  unsigned short* W1B1 = WhhF + 12288;                               // 2048
  unsigned short* W1B2 = W1B1 + 2048;                                // 2048
  int*   iws    = (int*)(W1B2 + 2048);
  int*   cnt    = iws;                          // N
  int*   off    = cnt + N;                      // N+1
  int*   cur    = off + N + 1;                  // N
  int*   bsum   = cur + N;                      // up to 1024
  int*   gstart = bsum + 1024;                  // G+1

  int B1 = (N + CH - 1) / CH;

  hipMemsetAsync(cnt, 0, (size_t)N*sizeof(int), stream);
  hipMemsetAsync(degf + N, 0, 16*sizeof(float), stream);

  count_kernel<<<(E+255)/256, 256, 0, stream>>>(ei, cnt, E);
  scan_partial<<<B1, 256, 0, stream>>>(cnt, bsum, N);
  scan_bsum<<<1, 64, 0, stream>>>(bsum, B1);
  scan_final<<<B1, 256, 0, stream>>>(cnt, bsum, off, cur, degf, N, E);
  fill_kernel<<<(E+255)/256, 256, 0, stream>>>(ei, x, ea, cur, csr2, E);

  pack_w1<<<8, 256, 0, stream>>>(mW1, W1B1, W1B2);
  make_M<<<48, 256, 0, stream>>>(Wih, mW2, mb2, M, dv);
  pack_frag<<<48, 256, 0, stream>>>(M, MF);
  pack_frag<<<48, 256, 0, stream>>>(Whh, WhhF);

  node_msg_kernel<<<1024, 256, 0, stream>>>(csr2, off, W1B1, W1B2, mb1, hsum, N);
  gru_mfma<<<512, 256, 0, stream>>>(hsum, MF, WhhF, bih, bhh, dv, degf, N);

  gstart_kernel<<<(G+256)/256, 256, 0, stream>>>(batch, gstart, N, G);
  pool_kernel<<<G, 64, 0, stream>>>(hsum, gstart, pooled, G);
  readout_kernel<<<(G+255)/256, 256, 0, stream>>>(pooled, rW1, rb1, rW2, rb2, out, G);
}

// Round 7
// 408.703 us; speedup vs baseline: 15.8098x; 1.0026x over previous
//
#include <hip/hip_runtime.h>
#include <math.h>

#define CH 1024

typedef __attribute__((ext_vector_type(8))) short bf16x8;
typedef __attribute__((ext_vector_type(4))) float f32x4;

__device__ __forceinline__ float sigmoidf_(float x){ return 1.0f/(1.0f+__expf(-x)); }
__device__ __forceinline__ float tanhf_(float x){ return 1.0f - 2.0f/(1.0f+__expf(2.0f*x)); }
__device__ __forceinline__ unsigned short f2bf(float f){
  union{float f;unsigned u;}v; v.f=f;
  unsigned r = v.u + 0x7fffu + ((v.u>>16)&1u);
  return (unsigned short)(r>>16);
}
__device__ __forceinline__ float bf2f(unsigned short u){
  union{unsigned u; float f;} v; v.u = ((unsigned)u) << 16; return v.f;
}

// ---------- CSR build ----------
__global__ __launch_bounds__(256) void count_kernel(const int* __restrict__ ei, int* __restrict__ cnt, int E){
  int e = blockIdx.x*256 + threadIdx.x;
  if (e < E) atomicAdd(&cnt[ei[E + e]], 1);
}

__global__ __launch_bounds__(256) void scan_partial(const int* __restrict__ cnt, int* __restrict__ bsum, int N){
  __shared__ int s[256];
  int b = blockIdx.x, t = threadIdx.x;
  int base = b*CH;
  int sum = 0;
  for (int i = t; i < CH; i += 256){ int idx = base + i; sum += (idx < N) ? cnt[idx] : 0; }
  s[t] = sum; __syncthreads();
  for (int off = 128; off > 0; off >>= 1){ if (t < off) s[t] += s[t+off]; __syncthreads(); }
  if (t == 0) bsum[b] = s[0];
}

__global__ void scan_bsum(int* __restrict__ bsum, int B){
  if (threadIdx.x == 0 && blockIdx.x == 0){
    int acc = 0;
    for (int i = 0; i < B; i++){ int v = bsum[i]; bsum[i] = acc; acc += v; }
  }
}

__global__ __launch_bounds__(256) void scan_final(const int* __restrict__ cnt, const int* __restrict__ bsum,
                                                  int* __restrict__ off, int* __restrict__ cur,
                                                  float* __restrict__ degf, int N, int E){
  __shared__ int s[256];
  __shared__ int sx[256];
  int b = blockIdx.x, t = threadIdx.x;
  int i0 = b*CH + t*4;
  int v0 = (i0   < N) ? cnt[i0]   : 0;
  int v1 = (i0+1 < N) ? cnt[i0+1] : 0;
  int v2 = (i0+2 < N) ? cnt[i0+2] : 0;
  int v3 = (i0+3 < N) ? cnt[i0+3] : 0;
  s[t] = v0+v1+v2+v3; __syncthreads();
  if (t == 0){ int acc = bsum[b]; for (int i = 0; i < 256; i++){ sx[i] = acc; acc += s[i]; } }
  __syncthreads();
  int acc = sx[t];
  if (i0   < N){ off[i0]   = acc; cur[i0]   = acc; degf[i0]   = (float)v0; } acc += v0;
  if (i0+1 < N){ off[i0+1] = acc; cur[i0+1] = acc; degf[i0+1] = (float)v1; } acc += v1;
  if (i0+2 < N){ off[i0+2] = acc; cur[i0+2] = acc; degf[i0+2] = (float)v2; } acc += v2;
  if (i0+3 < N){ off[i0+3] = acc; cur[i0+3] = acc; degf[i0+3] = (float)v3; }
  if (b == 0 && t == 0) off[N] = E;
}

// fill packed CSR rows: csr2[p][0..11] = {x[src][0..8], ea[e][0..2]}  (48B, f4-aligned)
__global__ __launch_bounds__(256) void fill_kernel(const int* __restrict__ ei, const float* __restrict__ x,
                                                   const float* __restrict__ ea,
                                                   int* __restrict__ cur, float* __restrict__ csr2, int E){
  int e = blockIdx.x*256 + threadIdx.x;
  if (e < E){
    int src = ei[e];
    int p = atomicAdd(&cur[ei[E + e]], 1);
    const float* xr = x + (size_t)src*9;
    float4 f0 = make_float4(xr[0], xr[1], xr[2], xr[3]);
    float4 f1 = make_float4(xr[4], xr[5], xr[6], xr[7]);
    float4 f2 = make_float4(xr[8], ea[e*3], ea[e*3+1], ea[e*3+2]);
    float4* row = (float4*)(csr2 + (size_t)p*12);
    row[0] = f0; row[1] = f1; row[2] = f2;
  }
}

// pack a [192][64] gate matrix (natural [n][k]) into bf16 B-fragments:
// P[((c*2+kh)*64 + lane)*8 + j] = bf16(W[(c*16 + (lane&15))*64 + kh*32 + 8*(lane>>4) + j])
__global__ __launch_bounds__(256) void pack_frag(const float* __restrict__ W, unsigned short* __restrict__ P){
  int o = blockIdx.x*256 + threadIdx.x;
  if (o >= 12288) return;
  int j = o & 7, l = (o>>3)&63, kh = (o>>9)&1, c = o>>10;
  P[o] = f2bf(W[(c*16 + (l&15))*64 + kh*32 + 8*(l>>4) + j]);
}

// W1 [64][12] -> two B-fragment sets over K=32:
// B1: k0..11 = W1_hi, k16..27 = W1_hi (for the ml half);  B2: k0..11 = W1_lo, else 0.
__global__ __launch_bounds__(256) void pack_w1(const float* __restrict__ W1,
    unsigned short* __restrict__ B1, unsigned short* __restrict__ B2){
  int o = blockIdx.x*256 + threadIdx.x;
  if (o >= 2048) return;
  int j = o & 7, l = (o>>3) & 63, c = o >> 9;
  int n = c*16 + (l & 15);
  int kk = 8*(l>>4) + j;
  unsigned short b1v = 0, b2v = 0;
  if (kk < 12){
    float w = W1[n*12 + kk];
    unsigned short hi = f2bf(w);
    b1v = hi;
    b2v = f2bf(w - bf2f(hi));
  } else if (kk >= 16 && kk < 28){
    b1v = f2bf(W1[n*12 + (kk-16)]);
  }
  B1[o] = b1v; B2[o] = b2v;
}

// M = Wih @ W2 (192x64), dv = Wih @ b2 (192)
__global__ __launch_bounds__(256) void make_M(const float* __restrict__ Wih, const float* __restrict__ W2,
    const float* __restrict__ b2, float* __restrict__ M, float* __restrict__ dv){
  int idx = blockIdx.x*256 + threadIdx.x;
  if (idx >= 12288) return;
  int o = idx >> 6, k = idx & 63;
  float acc = 0.0f;
  for (int j = 0; j < 64; j++) acc += Wih[o*64+j]*W2[j*64+k];
  M[idx] = acc;
  if (k == 0){
    float a2 = 0.0f;
    for (int j = 0; j < 64; j++) a2 += Wih[o*64+j]*b2[j];
    dv[o] = a2;
  }
}

// ---------- per-node layer-1 + segment-sum on MFMA (16-edge tiles, hi/lo split) ----------
__global__ __launch_bounds__(256, 2) void node_msg_kernel(
    const float* __restrict__ csr2, const int* __restrict__ off,
    const unsigned short* __restrict__ W1B1v, const unsigned short* __restrict__ W1B2v,
    const float* __restrict__ b1, float* __restrict__ hsum, int N)
{
  int t = threadIdx.x, lane = t & 63;
  int s_ = lane & 15, g_ = lane >> 4;
  const bf16x8* B1 = (const bf16x8*)W1B1v;
  const bf16x8* B2 = (const bf16x8*)W1B2v;
  bf16x8 w1b1[4], w1b2[4];
  #pragma unroll
  for (int c = 0; c < 4; c++){ w1b1[c] = B1[c*64+lane]; w1b2[c] = B2[c*64+lane]; }
  float b1f[4], rb1[4];
  #pragma unroll
  for (int c = 0; c < 4; c++){ b1f[c] = b1[c*16+s_]; rb1[c] = fmaxf(b1f[c], 0.f); }
  bool hi_ = (g_ < 2);
  int wid = (blockIdx.x*256 + t) >> 6;
  int nw = gridDim.x*4;
  for (int node = wid; node < N; node += nw){
    int s = off[node], e = off[node+1];
    float accR[4] = {0.f,0.f,0.f,0.f};
    int ntiles = (e - s + 15) >> 4;
    for (int tt = 0; tt < ntiles; tt++){
      int p = s + tt*16 + s_;
      float4 va = make_float4(0,0,0,0), vb = make_float4(0,0,0,0);
      if (p < e){
        const float4* row = (const float4*)(csr2 + (size_t)p*12);
        if ((g_ & 1) == 0){ va = row[0]; vb = row[1]; }
        else { va = row[2]; }
      }
      float mv[8] = {va.x,va.y,va.z,va.w,vb.x,vb.y,vb.z,vb.w};
      bf16x8 af, ah;
      #pragma unroll
      for (int i = 0; i < 8; i++){
        unsigned short mh = f2bf(mv[i]);
        unsigned short v;
        if (hi_) v = mh;
        else v = f2bf(mv[i] - bf2f(mh));
        af[i] = (short)v;
        ah[i] = hi_ ? (short)v : (short)0;
      }
      #pragma unroll
      for (int c = 0; c < 4; c++){
        f32x4 acc; acc[0]=b1f[c]; acc[1]=b1f[c]; acc[2]=b1f[c]; acc[3]=b1f[c];
        acc = __builtin_amdgcn_mfma_f32_16x16x32_bf16(af, w1b1[c], acc, 0,0,0);
        acc = __builtin_amdgcn_mfma_f32_16x16x32_bf16(ah, w1b2[c], acc, 0,0,0);
        accR[c] += fmaxf(acc[0],0.f)+fmaxf(acc[1],0.f)+fmaxf(acc[2],0.f)+fmaxf(acc[3],0.f);
      }
    }
    float npad = (float)(ntiles*16 - (e - s));
    #pragma unroll
    for (int c = 0; c < 4; c++){
      float v = accR[c] - npad*rb1[c];
      v += __shfl_xor(v, 16, 64);
      v += __shfl_xor(v, 32, 64);
      accR[c] = v;
    }
    float outv = (g_==0) ? accR[0] : ((g_==1) ? accR[1] : ((g_==2) ? accR[2] : accR[3]));
    hsum[(size_t)node*64 + lane] = outv;
  }
}

// ---------- fused (M@hsum + deg*dv + bih) + 6-step GRU on matrix cores ----------
// Whh fragments live in block-shared LDS (24 KB), not registers: sheds ~96 VGPRs
// so 3 waves/SIMD fit (R6: VGPR=248 -> 2/SIMD cap, 10% occupancy, latency-bound).
// One 16-node tile per wave (no loop) kills the tile-count tail imbalance.
__global__ __launch_bounds__(256, 1) void gru_mfma(
    float* hsumh,   // in: hsum [N][64]; out: h [N][64] (same buffer, per-tile in-place)
    const unsigned short* __restrict__ MF, const unsigned short* __restrict__ WhhF,
    const float* __restrict__ bih, const float* __restrict__ bhh,
    const float* __restrict__ dv, const float* __restrict__ degf, int N)
{
  __shared__ __align__(16) unsigned short swhh[12288];   // 24 KB: 24 fragments x 64 lanes x 8 bf16
  __shared__ unsigned short hbuf[4][1024];               // 8 KB: per-wave transpose buffer
  int t = threadIdx.x, lane = t & 63, w = t >> 6;
  int s_ = lane & 15, g_ = lane >> 4;
  unsigned short* hb = hbuf[w];

  // cooperative load of Whh fragments into LDS (uint4 = 8 ushorts)
  {
    const uint4* src = (const uint4*)WhhF;
    uint4* dst = (uint4*)swhh;
    #pragma unroll
    for (int i = 0; i < 6; i++) dst[t + 256*i] = src[t + 256*i];
  }
  __syncthreads();

  const bf16x8* WHH = (const bf16x8*)swhh;   // ds_read_b128 per use
  const bf16x8* MFV = (const bf16x8*)MF;

  float bi[12], bh[12], dvf[12];
  #pragma unroll
  for (int c = 0; c < 12; c++){ bi[c] = bih[c*16 + s_]; bh[c] = bhh[c*16 + s_]; dvf[c] = dv[c*16 + s_]; }

  int NT = (N + 15) >> 4;
  int tile = blockIdx.x*4 + w;
  if (tile >= NT) return;

  // ---- A-fragments of hsum tile (16 nodes x 64 feats) ----
  int nodeA = tile*16 + s_; if (nodeA > N-1) nodeA = N-1;
  const float* ab = hsumh + (size_t)nodeA*64 + g_*8;
  float4 v0 = *(const float4*)(ab);
  float4 v1 = *(const float4*)(ab+4);
  float4 v2 = *(const float4*)(ab+32);
  float4 v3 = *(const float4*)(ab+36);
  bf16x8 a0, a1;
  a0[0]=(short)f2bf(v0.x); a0[1]=(short)f2bf(v0.y); a0[2]=(short)f2bf(v0.z); a0[3]=(short)f2bf(v0.w);
  a0[4]=(short)f2bf(v1.x); a0[5]=(short)f2bf(v1.y); a0[6]=(short)f2bf(v1.z); a0[7]=(short)f2bf(v1.w);
  a1[0]=(short)f2bf(v2.x); a1[1]=(short)f2bf(v2.y); a1[2]=(short)f2bf(v2.z); a1[3]=(short)f2bf(v2.w);
  a1[4]=(short)f2bf(v3.x); a1[5]=(short)f2bf(v3.y); a1[6]=(short)f2bf(v3.z); a1[7]=(short)f2bf(v3.w);

  // ---- gi = M@hsum + deg*dv + bih, kept in registers ----
  float4 dr = *(const float4*)(degf + tile*16 + 4*g_);
  float drr[4] = {dr.x, dr.y, dr.z, dr.w};
  f32x4 gia[12];
  #pragma unroll
  for (int c = 0; c < 12; c++){
    f32x4 acc;
    #pragma unroll
    for (int r = 0; r < 4; r++) acc[r] = bi[c] + drr[r]*dvf[c];
    acc = __builtin_amdgcn_mfma_f32_16x16x32_bf16(a0, MFV[(c*2+0)*64 + lane], acc, 0, 0, 0);
    acc = __builtin_amdgcn_mfma_f32_16x16x32_bf16(a1, MFV[(c*2+1)*64 + lane], acc, 0, 0, 0);
    gia[c] = acc;
  }

  // ---- 6 GRU steps ----
  f32x4 hD[4];
  #pragma unroll
  for (int c = 0; c < 4; c++){ hD[c][0]=0.f; hD[c][1]=0.f; hD[c][2]=0.f; hD[c][3]=0.f; }
  bf16x8 h0 = {0,0,0,0,0,0,0,0};
  bf16x8 h1 = {0,0,0,0,0,0,0,0};
  for (int st = 0; st < 6; st++){
    #pragma unroll
    for (int c = 0; c < 4; c++){
      f32x4 aR, aZ, aN;
      aR[0]=bh[c];   aR[1]=bh[c];   aR[2]=bh[c];   aR[3]=bh[c];
      aZ[0]=bh[4+c]; aZ[1]=bh[4+c]; aZ[2]=bh[4+c]; aZ[3]=bh[4+c];
      aN[0]=bh[8+c]; aN[1]=bh[8+c]; aN[2]=bh[8+c]; aN[3]=bh[8+c];
      aR = __builtin_amdgcn_mfma_f32_16x16x32_bf16(h0, WHH[(c*2)*64 + lane],       aR, 0,0,0);
      aR = __builtin_amdgcn_mfma_f32_16x16x32_bf16(h1, WHH[(c*2+1)*64 + lane],     aR, 0,0,0);
      aZ = __builtin_amdgcn_mfma_f32_16x16x32_bf16(h0, WHH[((4+c)*2)*64 + lane],   aZ, 0,0,0);
      aZ = __builtin_amdgcn_mfma_f32_16x16x32_bf16(h1, WHH[((4+c)*2+1)*64 + lane], aZ, 0,0,0);
      aN = __builtin_amdgcn_mfma_f32_16x16x32_bf16(h0, WHH[((8+c)*2)*64 + lane],   aN, 0,0,0);
      aN = __builtin_amdgcn_mfma_f32_16x16x32_bf16(h1, WHH[((8+c)*2+1)*64 + lane], aN, 0,0,0);
      #pragma unroll
      for (int r = 0; r < 4; r++){
        float rr = sigmoidf_(gia[c][r]   + aR[r]);
        float zz = sigmoidf_(gia[4+c][r] + aZ[r]);
        float nn = tanhf_(gia[8+c][r] + rr*aN[r]);
        hD[c][r] = (1.0f - zz)*nn + zz*hD[c][r];
      }
    }
    if (st < 5){
      #pragma unroll
      for (int c = 0; c < 4; c++){
        #pragma unroll
        for (int r = 0; r < 4; r++){
          int nl = 4*g_ + r;
          int idx = (nl*64 + 16*c + s_) ^ ((nl & 7) << 3);
          hb[idx] = f2bf(hD[c][r]);
        }
      }
      int r0 = (s_*64 +      8*g_) ^ ((s_ & 7) << 3);
      int r1 = (s_*64 + 32 + 8*g_) ^ ((s_ & 7) << 3);
      h0 = *(const bf16x8*)(hb + r0);
      h1 = *(const bf16x8*)(hb + r1);
    }
  }
  // ---- store h (overwrites this tile's hsum rows; tiles are disjoint) ----
  #pragma unroll
  for (int c = 0; c < 4; c++){
    #pragma unroll
    for (int r = 0; r < 4; r++){
      int node = tile*16 + 4*g_ + r;
      if (node < N) hsumh[(size_t)node*64 + 16*c + s_] = hD[c][r];
    }
  }
}

// ---------- graph ranges via binary search on sorted batch ----------
__global__ __launch_bounds__(256) void gstart_kernel(const int* __restrict__ batch, int* __restrict__ gstart, int N, int G){
  int g = blockIdx.x*256 + threadIdx.x;
  if (g > G) return;
  int lo = 0, hi = N;
  while (lo < hi){ int mid = (lo + hi) >> 1; if (batch[mid] < g) lo = mid + 1; else hi = mid; }
  gstart[g] = lo;
}

// wave per graph: mean over the graph's node range
__global__ __launch_bounds__(64) void pool_kernel(const float* __restrict__ hout, const int* __restrict__ gstart,
                                                  float* __restrict__ pooled, int G){
  int g = blockIdx.x; int lane = threadIdx.x;
  int s = gstart[g], e = gstart[g+1];
  float acc = 0.0f;
  for (int n = s; n < e; n++) acc += hout[(size_t)n*64 + lane];
  float c = fmaxf((float)(e - s), 1.0f);
  pooled[g*64 + lane] = acc / c;
}

// thread per graph: out = W2 relu(W1 pooled + b1) + b2
__global__ __launch_bounds__(256) void readout_kernel(
  const float* __restrict__ pooled,
  const float* __restrict__ W1, const float* __restrict__ b1,
  const float* __restrict__ W2, const float* __restrict__ b2,
  float* __restrict__ out, int G)
{
  __shared__ __align__(16) float sW1[64*64];
  __shared__ float sb1[64], sW2v[64];
  for (int i = threadIdx.x; i < 64*64; i += 256) sW1[i] = W1[i];
  if (threadIdx.x < 64){ sb1[threadIdx.x] = b1[threadIdx.x]; sW2v[threadIdx.x] = W2[threadIdx.x]; }
  __syncthreads();
  int g = blockIdx.x*256 + threadIdx.x;
  if (g >= G) return;
  float p[64];
  const float4* pp = (const float4*)(pooled + g*64);
  #pragma unroll
  for (int k4 = 0; k4 < 16; k4++){
    float4 v = pp[k4];
    p[4*k4] = v.x; p[4*k4+1] = v.y; p[4*k4+2] = v.z; p[4*k4+3] = v.w;
  }
  float acc = b2[0];
  for (int j = 0; j < 64; j++){
    const float4* wv4 = (const float4*)(sW1 + j*64);
    float tacc = sb1[j];
    #pragma unroll
    for (int k4 = 0; k4 < 16; k4++){
      float4 wv = wv4[k4];
      tacc += wv.x*p[4*k4] + wv.y*p[4*k4+1] + wv.z*p[4*k4+2] + wv.w*p[4*k4+3];
    }
    acc += sW2v[j]*fmaxf(tacc, 0.0f);
  }
  out[g] = acc;
}

extern "C" void kernel_launch(void* const* d_in, const int* in_sizes, int n_in,
                              void* d_out, int out_size, void* d_ws, size_t ws_size,
                              hipStream_t stream)
{
  const float* x    = (const float*)d_in[0];
  const int*   ei   = (const int*)  d_in[1];
  const float* ea   = (const float*)d_in[2];
  const int*   batch= (const int*)  d_in[3];
  const float* mW1  = (const float*)d_in[4];
  const float* mb1  = (const float*)d_in[5];
  const float* mW2  = (const float*)d_in[6];
  const float* mb2  = (const float*)d_in[7];
  const float* Wih  = (const float*)d_in[8];
  const float* Whh  = (const float*)d_in[9];
  const float* bih  = (const float*)d_in[10];
  const float* bhh  = (const float*)d_in[11];
  const float* rW1  = (const float*)d_in[12];
  const float* rb1  = (const float*)d_in[13];
  const float* rW2  = (const float*)d_in[14];
  const float* rb2  = (const float*)d_in[15];
  float* out = (float*)d_out;

  int N = in_sizes[0] / 9;
  int E = in_sizes[1] / 2;
  int G = out_size;

  float* fws    = (float*)d_ws;
  float* hsum   = fws;                          // 64N floats (in: hsum, out: h)
  float* csr2   = hsum + (size_t)64*N;          // 12E floats
  float* degf   = csr2 + (size_t)12*E;          // N+16
  float* M      = degf + (size_t)(N+16);        // 12288
  float* dv     = M + 12288;                    // 192
  float* pooled = dv + 192;                     // 64G
  unsigned short* MF   = (unsigned short*)(pooled + (size_t)64*G);  // 12288
  unsigned short* WhhF = MF + 12288;                                 // 12288
  unsigned short* W1B1 = WhhF + 12288;                               // 2048
  unsigned short* W1B2 = W1B1 + 2048;                                // 2048
  int*   iws    = (int*)(W1B2 + 2048);
  int*   cnt    = iws;                          // N
  int*   off    = cnt + N;                      // N+1
  int*   cur    = off + N + 1;                  // N
  int*   bsum   = cur + N;                      // up to 1024
  int*   gstart = bsum + 1024;                  // G+1

  int B1 = (N + CH - 1) / CH;

  hipMemsetAsync(cnt, 0, (size_t)N*sizeof(int), stream);
  hipMemsetAsync(degf + N, 0, 16*sizeof(float), stream);

  count_kernel<<<(E+255)/256, 256, 0, stream>>>(ei, cnt, E);
  scan_partial<<<B1, 256, 0, stream>>>(cnt, bsum, N);
  scan_bsum<<<1, 64, 0, stream>>>(bsum, B1);
  scan_final<<<B1, 256, 0, stream>>>(cnt, bsum, off, cur, degf, N, E);
  fill_kernel<<<(E+255)/256, 256, 0, stream>>>(ei, x, ea, cur, csr2, E);

  pack_w1<<<8, 256, 0, stream>>>(mW1, W1B1, W1B2);
  make_M<<<48, 256, 0, stream>>>(Wih, mW2, mb2, M, dv);
  pack_frag<<<48, 256, 0, stream>>>(M, MF);
  pack_frag<<<48, 256, 0, stream>>>(Whh, WhhF);

  node_msg_kernel<<<1024, 256, 0, stream>>>(csr2, off, W1B1, W1B2, mb1, hsum, N);

  int NT = (N + 15) >> 4;
  gru_mfma<<<(NT + 3)/4, 256, 0, stream>>>(hsum, MF, WhhF, bih, bhh, dv, degf, N);

  gstart_kernel<<<(G+256)/256, 256, 0, stream>>>(batch, gstart, N, G);
  pool_kernel<<<G, 64, 0, stream>>>(hsum, gstart, pooled, G);
  readout_kernel<<<(G+255)/256, 256, 0, stream>>>(pooled, rW1, rb1, rW2, rb2, out, G);
}